// Round 2
// baseline (224.081 us; speedup 1.0000x reference)
//
#include <hip/hip_runtime.h>
#include <stdint.h>

// QuantizedLinear: out[N,OUT_F] = requant(int8gemm(x, W^T) + bias)
// x: [8192,4096] int8 (pushed as int32), W: [4096,4096] int8 (pushed as int32)
// out: int8 values stored as int32 (harness reads d_out as np.int32)

#define M_DIM 8192
#define N_DIM 4096
#define K_DIM 4096
#define BM 128
#define BN 128
#define BK 64   // int8 elements per K-tile

using i32x4 = __attribute__((ext_vector_type(4))) int;

typedef const __attribute__((address_space(1))) uint32_t* gptr_t;
typedef __attribute__((address_space(3))) uint32_t* lptr_t;

__device__ __forceinline__ void gload_lds16(const void* g, void* l) {
    __builtin_amdgcn_global_load_lds((gptr_t)g, (lptr_t)l, 16, 0, 0);
}

__device__ __forceinline__ int pack4(i32x4 v) {
    return (int)(((unsigned)v.x & 0xFFu) | (((unsigned)v.y & 0xFFu) << 8) |
                 (((unsigned)v.z & 0xFFu) << 16) | (((unsigned)v.w) << 24));
}

// int32 (sign-extended int8) -> packed int8
__global__ void pack_i8_kernel(const int* __restrict__ src, int8_t* __restrict__ dst, int n_elems) {
    int idx = blockIdx.x * blockDim.x + threadIdx.x;
    int stride = gridDim.x * blockDim.x;
    int n16 = n_elems >> 4;
    for (int i = idx; i < n16; i += stride) {
        const i32x4* s = (const i32x4*)(src + (size_t)i * 16);
        i32x4 v0 = s[0], v1 = s[1], v2 = s[2], v3 = s[3];
        i32x4 o;
        o.x = pack4(v0); o.y = pack4(v1); o.z = pack4(v2); o.w = pack4(v3);
        *(i32x4*)(dst + (size_t)i * 16) = o;
    }
}

// PACKED=true: xp/wp are packed int8, use global_load_lds staging (m97 structure)
// PACKED=false: xp/wp are int32, convert during staging (no workspace needed)
template<bool PACKED>
__global__ void qgemm_kernel(const void* __restrict__ xp, const void* __restrict__ wp,
                             const int* __restrict__ bias, const float* __restrict__ wscale,
                             const float* __restrict__ iscale, const float* __restrict__ oscale,
                             const int* __restrict__ zp, int* __restrict__ out) {
    __shared__ int8_t As[BM][BK];  // 8 KB, row stride 64B (contiguous for global_load_lds)
    __shared__ int8_t Bs[BN][BK];  // 8 KB

    const int tid  = threadIdx.x;
    const int wave = tid >> 6;
    const int lane = tid & 63;

    // XCD-bijective swizzle (gridDim.x = 2048, divisible by 8)
    int b = blockIdx.x;
    int s = (b & 7) * (gridDim.x >> 3) + (b >> 3);
    const int bcol = (s & 31) * BN;   // N_DIM/BN = 32
    const int brow = (s >> 5) * BM;

    const int wr = wave >> 1;         // 2x2 wave grid, each wave owns 64x64
    const int wc = wave & 1;

    i32x4 acc[4][4] = {};

    for (int kt = 0; kt < K_DIM; kt += BK) {
        if constexpr (PACKED) {
            const int8_t* x8 = (const int8_t*)xp;
            const int8_t* w8 = (const int8_t*)wp;
            #pragma unroll
            for (int i = 0; i < 2; i++) {
                int c = wave * 2 + i;                 // chunk 0..7, 1KB each = 16 rows
                int row = c * 16 + (lane >> 2);
                int colb = (lane & 3) * 16;
                gload_lds16(x8 + (size_t)(brow + row) * K_DIM + kt + colb, &As[c * 16][0]);
                gload_lds16(w8 + (size_t)(bcol + row) * K_DIM + kt + colb, &Bs[c * 16][0]);
            }
        } else {
            const int* x32 = (const int*)xp;
            const int* w32 = (const int*)wp;
            int row = tid >> 1;        // 0..127
            int h = tid & 1;           // 32-element half of the 64-wide K-tile
            const i32x4* sa = (const i32x4*)(x32 + (size_t)(brow + row) * K_DIM + kt + h * 32);
            const i32x4* sb = (const i32x4*)(w32 + (size_t)(bcol + row) * K_DIM + kt + h * 32);
            int pa[8], pb[8];
            #pragma unroll
            for (int j = 0; j < 8; j++) { pa[j] = pack4(sa[j]); pb[j] = pack4(sb[j]); }
            *(i32x4*)&As[row][h * 32]      = *(i32x4*)&pa[0];
            *(i32x4*)&As[row][h * 32 + 16] = *(i32x4*)&pa[4];
            *(i32x4*)&Bs[row][h * 32]      = *(i32x4*)&pb[0];
            *(i32x4*)&Bs[row][h * 32 + 16] = *(i32x4*)&pb[4];
        }
        __syncthreads();

        i32x4 a_frag[4], b_frag[4];
        #pragma unroll
        for (int m = 0; m < 4; m++)
            a_frag[m] = *(const i32x4*)&As[wr * 64 + m * 16 + (lane & 15)][(lane >> 4) * 16];
        #pragma unroll
        for (int n = 0; n < 4; n++)
            b_frag[n] = *(const i32x4*)&Bs[wc * 64 + n * 16 + (lane & 15)][(lane >> 4) * 16];

        #pragma unroll
        for (int m = 0; m < 4; m++)
            #pragma unroll
            for (int n = 0; n < 4; n++)
                acc[m][n] = __builtin_amdgcn_mfma_i32_16x16x64_i8(a_frag[m], b_frag[n], acc[m][n], 0, 0, 0);

        __syncthreads();
    }

    // Epilogue: out = clip(round((acc + bias) * (is*ws/os) + zp), -128, 127) as int32
    const float is_v = iscale[0];
    const float os_v = oscale[0];
    const float zpf = (float)zp[0];
    #pragma unroll
    for (int n = 0; n < 4; n++) {
        int col = bcol + wc * 64 + n * 16 + (lane & 15);
        float sf = (is_v * wscale[col]) / os_v;   // match reference association
        int bz = bias[col];
        #pragma unroll
        for (int m = 0; m < 4; m++) {
            int row0 = brow + wr * 64 + m * 16 + (lane >> 4) * 4;
            #pragma unroll
            for (int r = 0; r < 4; r++) {
                float v = (float)(acc[m][n][r] + bz) * sf + zpf;
                v = rintf(v);
                v = fminf(fmaxf(v, -128.0f), 127.0f);
                out[(size_t)(row0 + r) * N_DIM + col] = (int)v;
            }
        }
    }
}

extern "C" void kernel_launch(void* const* d_in, const int* in_sizes, int n_in,
                              void* d_out, int out_size, void* d_ws, size_t ws_size,
                              hipStream_t stream) {
    const int*   x32    = (const int*)d_in[0];
    const int*   w32    = (const int*)d_in[1];
    const int*   bias   = (const int*)d_in[2];
    const float* wscale = (const float*)d_in[3];
    const float* iscale = (const float*)d_in[4];
    const float* oscale = (const float*)d_in[5];
    const int*   zp     = (const int*)d_in[6];
    int* out = (int*)d_out;

    const size_t need = (size_t)M_DIM * K_DIM + (size_t)N_DIM * K_DIM;  // 50.3 MB
    const int nblocks = (M_DIM / BM) * (N_DIM / BN);  // 2048

    if (ws_size >= need) {
        int8_t* x8 = (int8_t*)d_ws;
        int8_t* w8 = x8 + (size_t)M_DIM * K_DIM;
        pack_i8_kernel<<<2048, 256, 0, stream>>>(x32, x8, M_DIM * K_DIM);
        pack_i8_kernel<<<1024, 256, 0, stream>>>(w32, w8, N_DIM * K_DIM);
        qgemm_kernel<true><<<nblocks, 256, 0, stream>>>(x8, w8, bias, wscale, iscale, oscale, zp, out);
    } else {
        qgemm_kernel<false><<<nblocks, 256, 0, stream>>>(x32, w32, bias, wscale, iscale, oscale, zp, out);
    }
}

// Round 3
// 220.476 us; speedup vs baseline: 1.0164x; 1.0164x over previous
//
#include <hip/hip_runtime.h>
#include <stdint.h>

// QuantizedLinear: out[N,OUT_F] = requant(int8gemm(x, W^T) + bias)
// x: [8192,4096] int8 (pushed int32), W: [4096,4096] int8 (pushed int32)
// out: int8 values stored as int32 (harness reads d_out as np.int32)
//
// Main GEMM: 128x256 tile, BK=128 i8, 8 waves (2Mx4N), 3-buffer LDS ring,
// phase-interleaved schedule (T3+T4 counted vmcnt), XOR-swizzled LDS (T2),
// setprio around MFMA clusters (T5), XCD-bijective block swizzle (T1).

#define M_DIM 8192
#define N_DIM 4096
#define K_DIM 4096
#define BM 128
#define BN 256
#define BKB 128                      // K-bytes (i8 elems) per tile
#define NT (K_DIM / BKB)             // 32 K-tile groups
#define NBLK ((M_DIM / BM) * (N_DIM / BN))   // 64*16 = 1024
#define ABUF (BM * BKB)              // 16 KiB
#define BBUF (BN * BKB)              // 32 KiB

using i32x4 = __attribute__((ext_vector_type(4))) int;

typedef const __attribute__((address_space(1))) uint32_t* gptr_t;
typedef __attribute__((address_space(3))) uint32_t* lptr_t;

__device__ __forceinline__ void gload_lds16(const void* g, void* l) {
    __builtin_amdgcn_global_load_lds((gptr_t)g, (lptr_t)l, 16, 0, 0);
}

__device__ __forceinline__ int pack4(i32x4 v) {
    return (int)(((unsigned)v.x & 0xFFu) | (((unsigned)v.y & 0xFFu) << 8) |
                 (((unsigned)v.z & 0xFFu) << 16) | (((unsigned)v.w) << 24));
}

// int32 (sign-extended int8) -> packed int8
__global__ void pack_i8_kernel(const int* __restrict__ src, int8_t* __restrict__ dst, int n_elems) {
    int idx = blockIdx.x * blockDim.x + threadIdx.x;
    int stride = gridDim.x * blockDim.x;
    int n16 = n_elems >> 4;
    for (int i = idx; i < n16; i += stride) {
        const i32x4* s = (const i32x4*)(src + (size_t)i * 16);
        i32x4 v0 = s[0], v1 = s[1], v2 = s[2], v3 = s[3];
        i32x4 o;
        o.x = pack4(v0); o.y = pack4(v1); o.z = pack4(v2); o.w = pack4(v3);
        *(i32x4*)(dst + (size_t)i * 16) = o;
    }
}

#define MFMA_I8(a, b, c) __builtin_amdgcn_mfma_i32_16x16x64_i8((a), (b), (c), 0, 0, 0)

// Fragment reads (swizzled): row&7 == lane&7 for all fragment rows.
#define RDA(m2, ks) (*(const i32x4*)(Acur + ((size_t)((qm)*32 + (m2)*16 + fr)) * BKB + ((((ks)*64 + fcol)) ^ fswz)))
#define RDB(n2, ks) (*(const i32x4*)(Bcur + ((size_t)((qn)*32 + (n2)*16 + fr)) * BKB + ((((ks)*64 + fcol)) ^ fswz)))

// One phase: ds-read quadrant frags, issue stage loads, barrier, drain lgkm,
// 8 MFMA under setprio, optional tail sync (vmcnt), barrier.
#define PHASE(qm_, qn_, STAGE_STMTS, TAIL_STMTS)                                  \
  { constexpr int qm = (qm_); constexpr int qn = (qn_);                           \
    i32x4 a00 = RDA(0,0), a01 = RDA(0,1), a10 = RDA(1,0), a11 = RDA(1,1);         \
    i32x4 b00 = RDB(0,0), b01 = RDB(0,1), b10 = RDB(1,0), b11 = RDB(1,1);         \
    STAGE_STMTS;                                                                  \
    __builtin_amdgcn_s_barrier();                                                 \
    asm volatile("s_waitcnt lgkmcnt(0)" ::: "memory");                            \
    __builtin_amdgcn_sched_barrier(0);                                            \
    __builtin_amdgcn_s_setprio(1);                                                \
    acc[qm*2+0][qn*2+0] = MFMA_I8(a00, b00, acc[qm*2+0][qn*2+0]);                 \
    acc[qm*2+0][qn*2+1] = MFMA_I8(a00, b10, acc[qm*2+0][qn*2+1]);                 \
    acc[qm*2+1][qn*2+0] = MFMA_I8(a10, b00, acc[qm*2+1][qn*2+0]);                 \
    acc[qm*2+1][qn*2+1] = MFMA_I8(a10, b10, acc[qm*2+1][qn*2+1]);                 \
    acc[qm*2+0][qn*2+0] = MFMA_I8(a01, b01, acc[qm*2+0][qn*2+0]);                 \
    acc[qm*2+0][qn*2+1] = MFMA_I8(a01, b11, acc[qm*2+0][qn*2+1]);                 \
    acc[qm*2+1][qn*2+0] = MFMA_I8(a11, b01, acc[qm*2+1][qn*2+0]);                 \
    acc[qm*2+1][qn*2+1] = MFMA_I8(a11, b11, acc[qm*2+1][qn*2+1]);                 \
    __builtin_amdgcn_s_setprio(0);                                                \
    TAIL_STMTS;                                                                   \
    __builtin_amdgcn_s_barrier();                                                 \
  }

__global__ __launch_bounds__(512, 2)
void qgemm8_kernel(const int8_t* __restrict__ x8, const int8_t* __restrict__ w8,
                   const int* __restrict__ bias, const float* __restrict__ wscale,
                   const float* __restrict__ iscale, const float* __restrict__ oscale,
                   const int* __restrict__ zp, int* __restrict__ out) {
    extern __shared__ int8_t lds[];
    int8_t* As = lds;                 // 3 * 16 KiB
    int8_t* Bs = lds + 3 * ABUF;      // 3 * 32 KiB

    const int tid  = threadIdx.x;
    const int wave = tid >> 6;
    const int lane = tid & 63;

    // XCD-bijective swizzle (NBLK = 1024, divisible by 8)
    int b = blockIdx.x;
    int s = (b & 7) * (NBLK >> 3) + (b >> 3);
    const int bcol = (s & 15) * BN;   // N_DIM/BN = 16
    const int brow = (s >> 4) * BM;

    const int wr = wave >> 2;         // 0..1  (M)
    const int wc = wave & 3;          // 0..3  (N)

    // ---- staging geometry: LDS dest linear; global source pre-swizzled (T2) ----
    const int sr8 = lane >> 3;                          // row&7 of staged row
    const int scs = ((lane & 7) * 16) ^ (sr8 << 4);     // swizzled 16B chunk in 128B row
    const int8_t* Ag = x8 + (size_t)(brow + wave * 16 + sr8) * K_DIM + scs;
    const int8_t* Bg = w8 + (size_t)(bcol + wave * 32 + sr8) * K_DIM + scs;
    const int aoff = wave * 2048;     // + j*1024 (+ lane*16 by HW)
    const int boff = wave * 4096;

    // ---- fragment read geometry ----
    const int fr   = lane & 15;
    const int fcol = (lane >> 4) * 16;
    const int fswz = (lane & 7) << 4;

    i32x4 acc[4][4] = {};

    // ---- prologue: stage tile0 -> buf0, tile1 -> buf1; land tile0 ----
    #pragma unroll
    for (int t0 = 0; t0 < 2; t0++) {
        int8_t* Ad = As + t0 * ABUF;
        int8_t* Bd = Bs + t0 * BBUF;
        const int8_t* Ak = Ag + (size_t)t0 * BKB;
        const int8_t* Bk = Bg + (size_t)t0 * BKB;
        gload_lds16(Ak,              Ad + aoff);
        gload_lds16(Ak + 8 * K_DIM,  Ad + aoff + 1024);
        gload_lds16(Bk,              Bd + boff);
        gload_lds16(Bk + 8 * K_DIM,  Bd + boff + 1024);
        gload_lds16(Bk + 16 * K_DIM, Bd + boff + 2048);
        gload_lds16(Bk + 24 * K_DIM, Bd + boff + 3072);
    }
    asm volatile("s_waitcnt vmcnt(6)" ::: "memory");   // tile0 landed; tile1 in flight
    __builtin_amdgcn_s_barrier();

    int cur = 0, stg = 2;
    // ---- main loop: groups t = 0 .. NT-3, staging tile t+2 into ring buf ----
    for (int t = 0; t < NT - 2; ++t) {
        const int8_t* Acur = As + cur * ABUF + (size_t)(wr * 64) * BKB;
        const int8_t* Bcur = Bs + cur * BBUF + (size_t)(wc * 64) * BKB;
        int8_t* Astg = As + stg * ABUF;
        int8_t* Bstg = Bs + stg * BBUF;
        const int8_t* AgK = Ag + (size_t)(t + 2) * BKB;
        const int8_t* BgK = Bg + (size_t)(t + 2) * BKB;

        PHASE(0, 0,
              { gload_lds16(AgK,             Astg + aoff);
                gload_lds16(BgK,             Bstg + boff); },
              ((void)0))
        PHASE(0, 1,
              { gload_lds16(AgK + 8 * K_DIM, Astg + aoff + 1024);
                gload_lds16(BgK + 8 * K_DIM, Bstg + boff + 1024); },
              ((void)0))
        PHASE(1, 0,
              { gload_lds16(BgK + 16 * K_DIM, Bstg + boff + 2048); },
              ((void)0))
        PHASE(1, 1,
              { gload_lds16(BgK + 24 * K_DIM, Bstg + boff + 3072); },
              asm volatile("s_waitcnt vmcnt(6)" ::: "memory"))   // tile t+1 landed

        cur = (cur == 2) ? 0 : cur + 1;
        stg = (stg == 2) ? 0 : stg + 1;
    }
    // ---- group NT-2: no staging; drain so tile NT-1 is landed ----
    {
        const int8_t* Acur = As + cur * ABUF + (size_t)(wr * 64) * BKB;
        const int8_t* Bcur = Bs + cur * BBUF + (size_t)(wc * 64) * BKB;
        PHASE(0, 0, ((void)0), ((void)0))
        PHASE(0, 1, ((void)0), ((void)0))
        PHASE(1, 0, ((void)0), ((void)0))
        PHASE(1, 1, ((void)0), asm volatile("s_waitcnt vmcnt(0)" ::: "memory"))
        cur = (cur == 2) ? 0 : cur + 1;
    }
    // ---- group NT-1: final compute ----
    {
        const int8_t* Acur = As + cur * ABUF + (size_t)(wr * 64) * BKB;
        const int8_t* Bcur = Bs + cur * BBUF + (size_t)(wc * 64) * BKB;
        PHASE(0, 0, ((void)0), ((void)0))
        PHASE(0, 1, ((void)0), ((void)0))
        PHASE(1, 0, ((void)0), ((void)0))
        PHASE(1, 1, ((void)0), ((void)0))
    }

    // ---- epilogue: out = clip(round((acc + bias) * (is*ws/os) + zp)) as int32 ----
    const float is_v = iscale[0];
    const float os_v = oscale[0];
    const float zpf = (float)zp[0];
    #pragma unroll
    for (int n = 0; n < 4; n++) {
        int col = bcol + wc * 64 + n * 16 + (lane & 15);
        float sf = (is_v * wscale[col]) / os_v;
        int bz = bias[col];
        #pragma unroll
        for (int m = 0; m < 4; m++) {
            int row0 = brow + wr * 64 + m * 16 + (lane >> 4) * 4;
            #pragma unroll
            for (int r = 0; r < 4; r++) {
                float v = (float)(acc[m][n][r] + bz) * sf + zpf;
                v = rintf(v);
                v = fminf(fmaxf(v, -128.0f), 127.0f);
                out[(size_t)(row0 + r) * N_DIM + col] = (int)v;
            }
        }
    }
}

// Fallback (no workspace): direct int32 consumption, 128^2 tile (round-2 proven).
__global__ void qgemm_fallback(const int* __restrict__ x32, const int* __restrict__ w32,
                               const int* __restrict__ bias, const float* __restrict__ wscale,
                               const float* __restrict__ iscale, const float* __restrict__ oscale,
                               const int* __restrict__ zp, int* __restrict__ out) {
    __shared__ int8_t As[128][64];
    __shared__ int8_t Bs[128][64];
    const int tid  = threadIdx.x;
    const int wave = tid >> 6;
    const int lane = tid & 63;
    int b = blockIdx.x;
    int s = (b & 7) * (gridDim.x >> 3) + (b >> 3);
    const int bcol = (s & 31) * 128;
    const int brow = (s >> 5) * 128;
    const int wr = wave >> 1;
    const int wc = wave & 1;
    i32x4 acc[4][4] = {};
    for (int kt = 0; kt < K_DIM; kt += 64) {
        int row = tid >> 1;
        int h = tid & 1;
        const i32x4* sa = (const i32x4*)(x32 + (size_t)(brow + row) * K_DIM + kt + h * 32);
        const i32x4* sb = (const i32x4*)(w32 + (size_t)(bcol + row) * K_DIM + kt + h * 32);
        int pa[8], pb[8];
        #pragma unroll
        for (int j = 0; j < 8; j++) { pa[j] = pack4(sa[j]); pb[j] = pack4(sb[j]); }
        *(i32x4*)&As[row][h * 32]      = *(i32x4*)&pa[0];
        *(i32x4*)&As[row][h * 32 + 16] = *(i32x4*)&pa[4];
        *(i32x4*)&Bs[row][h * 32]      = *(i32x4*)&pb[0];
        *(i32x4*)&Bs[row][h * 32 + 16] = *(i32x4*)&pb[4];
        __syncthreads();
        i32x4 a_frag[4], b_frag[4];
        #pragma unroll
        for (int m = 0; m < 4; m++)
            a_frag[m] = *(const i32x4*)&As[wr * 64 + m * 16 + (lane & 15)][(lane >> 4) * 16];
        #pragma unroll
        for (int n = 0; n < 4; n++)
            b_frag[n] = *(const i32x4*)&Bs[wc * 64 + n * 16 + (lane & 15)][(lane >> 4) * 16];
        #pragma unroll
        for (int m = 0; m < 4; m++)
            #pragma unroll
            for (int n = 0; n < 4; n++)
                acc[m][n] = MFMA_I8(a_frag[m], b_frag[n], acc[m][n]);
        __syncthreads();
    }
    const float is_v = iscale[0];
    const float os_v = oscale[0];
    const float zpf = (float)zp[0];
    #pragma unroll
    for (int n = 0; n < 4; n++) {
        int col = bcol + wc * 64 + n * 16 + (lane & 15);
        float sf = (is_v * wscale[col]) / os_v;
        int bz = bias[col];
        #pragma unroll
        for (int m = 0; m < 4; m++) {
            int row0 = brow + wr * 64 + m * 16 + (lane >> 4) * 4;
            #pragma unroll
            for (int r = 0; r < 4; r++) {
                float v = (float)(acc[m][n][r] + bz) * sf + zpf;
                v = rintf(v);
                v = fminf(fmaxf(v, -128.0f), 127.0f);
                out[(size_t)(row0 + r) * N_DIM + col] = (int)v;
            }
        }
    }
}

extern "C" void kernel_launch(void* const* d_in, const int* in_sizes, int n_in,
                              void* d_out, int out_size, void* d_ws, size_t ws_size,
                              hipStream_t stream) {
    const int*   x32    = (const int*)d_in[0];
    const int*   w32    = (const int*)d_in[1];
    const int*   bias   = (const int*)d_in[2];
    const float* wscale = (const float*)d_in[3];
    const float* iscale = (const float*)d_in[4];
    const float* oscale = (const float*)d_in[5];
    const int*   zp     = (const int*)d_in[6];
    int* out = (int*)d_out;

    const size_t need = (size_t)M_DIM * K_DIM + (size_t)N_DIM * K_DIM;  // 50.3 MB
    const size_t lds_bytes = 3 * (size_t)(ABUF + BBUF);                 // 147456

    if (ws_size >= need) {
        int8_t* x8 = (int8_t*)d_ws;
        int8_t* w8 = x8 + (size_t)M_DIM * K_DIM;
        pack_i8_kernel<<<2048, 256, 0, stream>>>(x32, x8, M_DIM * K_DIM);
        pack_i8_kernel<<<1024, 256, 0, stream>>>(w32, w8, N_DIM * K_DIM);
        (void)hipFuncSetAttribute((const void*)qgemm8_kernel,
                                  hipFuncAttributeMaxDynamicSharedMemorySize,
                                  (int)lds_bytes);
        qgemm8_kernel<<<NBLK, 512, lds_bytes, stream>>>(x8, w8, bias, wscale, iscale, oscale, zp, out);
    } else {
        qgemm_fallback<<<2048, 256, 0, stream>>>(x32, w32, bias, wscale, iscale, oscale, zp, out);
    }
}

// Round 4
// 201.352 us; speedup vs baseline: 1.1129x; 1.0950x over previous
//
#include <hip/hip_runtime.h>
#include <stdint.h>

// QuantizedLinear: out[N,OUT_F] = requant(int8gemm(x, W^T) + bias)
// x: [8192,4096] int8 (pushed int32), W: [4096,4096] int8 (pushed int32)
// out: int8 values stored as int32 (harness reads d_out as np.int32)
//
// Main GEMM (r4): 256x256 tile, 8 waves (2Mx4N), per-wave 128x64 output,
// BK=64 i8, 3-buffer LDS ring (96 KiB), 2 phases/K-tile x 16 MFMA,
// each fragment ds_read exactly once (B held in regs across phases),
// counted vmcnt (T4), setprio around MFMA (T5), XCD-bijective swizzle (T1).

#define M_DIM 8192
#define N_DIM 4096
#define K_DIM 4096
#define BM 256
#define BN 256
#define BKB 64                       // K-bytes (i8 elems) per tile
#define NT (K_DIM / BKB)             // 64 K-tiles
#define NBLK ((M_DIM / BM) * (N_DIM / BN))   // 32*16 = 512
#define ABUF (BM * BKB)              // 16 KiB
#define BBUF (BN * BKB)              // 16 KiB

using i32x4 = __attribute__((ext_vector_type(4))) int;

typedef const __attribute__((address_space(1))) uint32_t* gptr_t;
typedef __attribute__((address_space(3))) uint32_t* lptr_t;

__device__ __forceinline__ void gload_lds16(const void* g, void* l) {
    __builtin_amdgcn_global_load_lds((gptr_t)g, (lptr_t)l, 16, 0, 0);
}

__device__ __forceinline__ int pack4(i32x4 v) {
    return (int)(((unsigned)v.x & 0xFFu) | (((unsigned)v.y & 0xFFu) << 8) |
                 (((unsigned)v.z & 0xFFu) << 16) | (((unsigned)v.w) << 24));
}

// int32 (sign-extended int8) -> packed int8
__global__ void pack_i8_kernel(const int* __restrict__ src, int8_t* __restrict__ dst, int n_elems) {
    int idx = blockIdx.x * blockDim.x + threadIdx.x;
    int stride = gridDim.x * blockDim.x;
    int n16 = n_elems >> 4;
    for (int i = idx; i < n16; i += stride) {
        const i32x4* s = (const i32x4*)(src + (size_t)i * 16);
        i32x4 v0 = s[0], v1 = s[1], v2 = s[2], v3 = s[3];
        i32x4 o;
        o.x = pack4(v0); o.y = pack4(v1); o.z = pack4(v2); o.w = pack4(v3);
        *(i32x4*)(dst + (size_t)i * 16) = o;
    }
}

#define MFMA_I8(a, b, c) __builtin_amdgcn_mfma_i32_16x16x64_i8((a), (b), (c), 0, 0, 0)

// Fragment reads: contiguous 1KB per wave instruction (rows are 64B) -> no swizzle.
#define FRAG_A(P, m) (*(const i32x4*)(Acur + ((wr * 128 + (P) * 64 + (m) * 16 + fr) * 64 + fcol)))
#define FRAG_B(n)    (*(const i32x4*)(Bcur + ((wc * 64 + (n) * 16 + fr) * 64 + fcol)))

// Phase P=0: read A m0-3 + all B (kept live), 16 MFMA into acc[0..3][*]
#define PHASE0(STAGE_STMTS, TAIL_STMTS)                                           \
  { i32x4 af0 = FRAG_A(0,0), af1 = FRAG_A(0,1), af2 = FRAG_A(0,2), af3 = FRAG_A(0,3); \
    bq0 = FRAG_B(0); bq1 = FRAG_B(1); bq2 = FRAG_B(2); bq3 = FRAG_B(3);           \
    STAGE_STMTS;                                                                  \
    __builtin_amdgcn_s_barrier();                                                 \
    asm volatile("s_waitcnt lgkmcnt(0)" ::: "memory");                            \
    __builtin_amdgcn_sched_barrier(0);                                            \
    __builtin_amdgcn_s_setprio(1);                                                \
    acc[0][0]=MFMA_I8(af0,bq0,acc[0][0]); acc[0][1]=MFMA_I8(af0,bq1,acc[0][1]);   \
    acc[0][2]=MFMA_I8(af0,bq2,acc[0][2]); acc[0][3]=MFMA_I8(af0,bq3,acc[0][3]);   \
    acc[1][0]=MFMA_I8(af1,bq0,acc[1][0]); acc[1][1]=MFMA_I8(af1,bq1,acc[1][1]);   \
    acc[1][2]=MFMA_I8(af1,bq2,acc[1][2]); acc[1][3]=MFMA_I8(af1,bq3,acc[1][3]);   \
    acc[2][0]=MFMA_I8(af2,bq0,acc[2][0]); acc[2][1]=MFMA_I8(af2,bq1,acc[2][1]);   \
    acc[2][2]=MFMA_I8(af2,bq2,acc[2][2]); acc[2][3]=MFMA_I8(af2,bq3,acc[2][3]);   \
    acc[3][0]=MFMA_I8(af3,bq0,acc[3][0]); acc[3][1]=MFMA_I8(af3,bq1,acc[3][1]);   \
    acc[3][2]=MFMA_I8(af3,bq2,acc[3][2]); acc[3][3]=MFMA_I8(af3,bq3,acc[3][3]);   \
    __builtin_amdgcn_s_setprio(0);                                                \
    TAIL_STMTS;                                                                   \
    __builtin_amdgcn_s_barrier(); }

// Phase P=1: read A m4-7, reuse B regs, 16 MFMA into acc[4..7][*]
#define PHASE1(STAGE_STMTS, TAIL_STMTS)                                           \
  { i32x4 af0 = FRAG_A(1,0), af1 = FRAG_A(1,1), af2 = FRAG_A(1,2), af3 = FRAG_A(1,3); \
    STAGE_STMTS;                                                                  \
    __builtin_amdgcn_s_barrier();                                                 \
    asm volatile("s_waitcnt lgkmcnt(0)" ::: "memory");                            \
    __builtin_amdgcn_sched_barrier(0);                                            \
    __builtin_amdgcn_s_setprio(1);                                                \
    acc[4][0]=MFMA_I8(af0,bq0,acc[4][0]); acc[4][1]=MFMA_I8(af0,bq1,acc[4][1]);   \
    acc[4][2]=MFMA_I8(af0,bq2,acc[4][2]); acc[4][3]=MFMA_I8(af0,bq3,acc[4][3]);   \
    acc[5][0]=MFMA_I8(af1,bq0,acc[5][0]); acc[5][1]=MFMA_I8(af1,bq1,acc[5][1]);   \
    acc[5][2]=MFMA_I8(af1,bq2,acc[5][2]); acc[5][3]=MFMA_I8(af1,bq3,acc[5][3]);   \
    acc[6][0]=MFMA_I8(af2,bq0,acc[6][0]); acc[6][1]=MFMA_I8(af2,bq1,acc[6][1]);   \
    acc[6][2]=MFMA_I8(af2,bq2,acc[6][2]); acc[6][3]=MFMA_I8(af2,bq3,acc[6][3]);   \
    acc[7][0]=MFMA_I8(af3,bq0,acc[7][0]); acc[7][1]=MFMA_I8(af3,bq1,acc[7][1]);   \
    acc[7][2]=MFMA_I8(af3,bq2,acc[7][2]); acc[7][3]=MFMA_I8(af3,bq3,acc[7][3]);   \
    __builtin_amdgcn_s_setprio(0);                                                \
    TAIL_STMTS;                                                                   \
    __builtin_amdgcn_s_barrier(); }

__global__ __launch_bounds__(512, 2)
void qgemm256_kernel(const int8_t* __restrict__ x8, const int8_t* __restrict__ w8,
                     const int* __restrict__ bias, const float* __restrict__ wscale,
                     const float* __restrict__ iscale, const float* __restrict__ oscale,
                     const int* __restrict__ zp, int* __restrict__ out) {
    extern __shared__ int8_t lds[];
    int8_t* As = lds;                 // 3 * 16 KiB
    int8_t* Bs = lds + 3 * ABUF;      // 3 * 16 KiB

    const int tid  = threadIdx.x;
    const int wave = tid >> 6;
    const int lane = tid & 63;

    // XCD-bijective swizzle (NBLK = 512, divisible by 8)
    int b = blockIdx.x;
    int s = (b & 7) * (NBLK >> 3) + (b >> 3);
    const int bcol = (s & 15) * BN;   // N_DIM/BN = 16
    const int brow = (s >> 4) * BM;   // 32 block-rows

    const int wr = wave >> 2;         // 0..1  (M half, 128 rows)
    const int wc = wave & 3;          // 0..3  (N quarter, 64 cols)

    // ---- staging geometry: wave stages A rows [wave*32, wave*32+32), B same ----
    // chunk = 16 rows x 64B = 1KB per gload_lds issue; lane -> row (lane>>2), col chunk (lane&3)
    const int8_t* Ag = x8 + (size_t)(brow + wave * 32 + (lane >> 2)) * K_DIM + (lane & 3) * 16;
    const int8_t* Bg = w8 + (size_t)(bcol + wave * 32 + (lane >> 2)) * K_DIM + (lane & 3) * 16;
    const int aoff = wave * 2048;     // two 1KB chunks per wave (+ lane*16 by HW)
    const int boff = wave * 2048;

    // ---- fragment read geometry ----
    const int fr   = lane & 15;
    const int fcol = (lane >> 4) * 16;

    i32x4 acc[8][4] = {};
    i32x4 bq0, bq1, bq2, bq3;

    // ---- prologue: stage tile0 -> buf0, tile1 -> buf1 (4 loads/wave each) ----
    #pragma unroll
    for (int t0 = 0; t0 < 2; t0++) {
        int8_t* Ad = As + t0 * ABUF;
        int8_t* Bd = Bs + t0 * BBUF;
        const int8_t* Ak = Ag + (size_t)t0 * BKB;
        const int8_t* Bk = Bg + (size_t)t0 * BKB;
        gload_lds16(Ak,               Ad + aoff);
        gload_lds16(Ak + 16 * K_DIM,  Ad + aoff + 1024);
        gload_lds16(Bk,               Bd + boff);
        gload_lds16(Bk + 16 * K_DIM,  Bd + boff + 1024);
    }
    asm volatile("s_waitcnt vmcnt(4)" ::: "memory");   // tile0 landed; tile1 in flight
    __builtin_amdgcn_s_barrier();

    int cur = 0, stg = 2;
    // ---- main loop: t = 0 .. NT-3, staging tile t+2 into ring buffer ----
    for (int t = 0; t < NT - 2; ++t) {
        const int8_t* Acur = As + cur * ABUF;
        const int8_t* Bcur = Bs + cur * BBUF;
        int8_t* Astg = As + stg * ABUF;
        int8_t* Bstg = Bs + stg * BBUF;
        const int8_t* AgK = Ag + (size_t)(t + 2) * BKB;
        const int8_t* BgK = Bg + (size_t)(t + 2) * BKB;

        PHASE0(
            { gload_lds16(AgK,              Astg + aoff);
              gload_lds16(AgK + 16 * K_DIM, Astg + aoff + 1024); },
            ((void)0))
        PHASE1(
            { gload_lds16(BgK,              Bstg + boff);
              gload_lds16(BgK + 16 * K_DIM, Bstg + boff + 1024); },
            asm volatile("s_waitcnt vmcnt(4)" ::: "memory"))   // tile t+1 landed

        cur = (cur == 2) ? 0 : cur + 1;
        stg = (stg == 2) ? 0 : stg + 1;
    }
    // ---- t = NT-2: no staging; drain so tile NT-1 is landed ----
    {
        const int8_t* Acur = As + cur * ABUF;
        const int8_t* Bcur = Bs + cur * BBUF;
        PHASE0(((void)0), ((void)0))
        PHASE1(((void)0), asm volatile("s_waitcnt vmcnt(0)" ::: "memory"))
        cur = (cur == 2) ? 0 : cur + 1;
    }
    // ---- t = NT-1: final compute ----
    {
        const int8_t* Acur = As + cur * ABUF;
        const int8_t* Bcur = Bs + cur * BBUF;
        PHASE0(((void)0), ((void)0))
        PHASE1(((void)0), ((void)0))
    }

    // ---- epilogue: out = clip(round((acc + bias) * (is*ws/os) + zp)) as int32 ----
    const float is_v = iscale[0];
    const float os_v = oscale[0];
    const float zpf = (float)zp[0];
    #pragma unroll
    for (int n = 0; n < 4; n++) {
        int col = bcol + wc * 64 + n * 16 + (lane & 15);
        float sf = (is_v * wscale[col]) / os_v;
        int bz = bias[col];
        #pragma unroll
        for (int m = 0; m < 8; m++) {
            int row0 = brow + wr * 128 + m * 16 + (lane >> 4) * 4;
            #pragma unroll
            for (int r = 0; r < 4; r++) {
                float v = (float)(acc[m][n][r] + bz) * sf + zpf;
                v = rintf(v);
                v = fminf(fmaxf(v, -128.0f), 127.0f);
                out[(size_t)(row0 + r) * N_DIM + col] = (int)v;
            }
        }
    }
}

// Fallback (no workspace): direct int32 consumption, 128^2 tile (round-2 proven).
__global__ void qgemm_fallback(const int* __restrict__ x32, const int* __restrict__ w32,
                               const int* __restrict__ bias, const float* __restrict__ wscale,
                               const float* __restrict__ iscale, const float* __restrict__ oscale,
                               const int* __restrict__ zp, int* __restrict__ out) {
    __shared__ int8_t As[128][64];
    __shared__ int8_t Bs[128][64];
    const int tid  = threadIdx.x;
    const int wave = tid >> 6;
    const int lane = tid & 63;
    int b = blockIdx.x;
    int s = (b & 7) * (gridDim.x >> 3) + (b >> 3);
    const int bcol = (s & 31) * 128;
    const int brow = (s >> 5) * 128;
    const int wr = wave >> 1;
    const int wc = wave & 1;
    i32x4 acc[4][4] = {};
    for (int kt = 0; kt < K_DIM; kt += 64) {
        int row = tid >> 1;
        int h = tid & 1;
        const i32x4* sa = (const i32x4*)(x32 + (size_t)(brow + row) * K_DIM + kt + h * 32);
        const i32x4* sb = (const i32x4*)(w32 + (size_t)(bcol + row) * K_DIM + kt + h * 32);
        int pa[8], pb[8];
        #pragma unroll
        for (int j = 0; j < 8; j++) { pa[j] = pack4(sa[j]); pb[j] = pack4(sb[j]); }
        *(i32x4*)&As[row][h * 32]      = *(i32x4*)&pa[0];
        *(i32x4*)&As[row][h * 32 + 16] = *(i32x4*)&pa[4];
        *(i32x4*)&Bs[row][h * 32]      = *(i32x4*)&pb[0];
        *(i32x4*)&Bs[row][h * 32 + 16] = *(i32x4*)&pb[4];
        __syncthreads();
        i32x4 a_frag[4], b_frag[4];
        #pragma unroll
        for (int m = 0; m < 4; m++)
            a_frag[m] = *(const i32x4*)&As[wr * 64 + m * 16 + (lane & 15)][(lane >> 4) * 16];
        #pragma unroll
        for (int n = 0; n < 4; n++)
            b_frag[n] = *(const i32x4*)&Bs[wc * 64 + n * 16 + (lane & 15)][(lane >> 4) * 16];
        #pragma unroll
        for (int m = 0; m < 4; m++)
            #pragma unroll
            for (int n = 0; n < 4; n++)
                acc[m][n] = MFMA_I8(a_frag[m], b_frag[n], acc[m][n]);
        __syncthreads();
    }
    const float is_v = iscale[0];
    const float os_v = oscale[0];
    const float zpf = (float)zp[0];
    #pragma unroll
    for (int n = 0; n < 4; n++) {
        int col = bcol + wc * 64 + n * 16 + (lane & 15);
        float sf = (is_v * wscale[col]) / os_v;
        int bz = bias[col];
        #pragma unroll
        for (int m = 0; m < 4; m++) {
            int row0 = brow + wr * 64 + m * 16 + (lane >> 4) * 4;
            #pragma unroll
            for (int r = 0; r < 4; r++) {
                float v = (float)(acc[m][n][r] + bz) * sf + zpf;
                v = rintf(v);
                v = fminf(fmaxf(v, -128.0f), 127.0f);
                out[(size_t)(row0 + r) * N_DIM + col] = (int)v;
            }
        }
    }
}

extern "C" void kernel_launch(void* const* d_in, const int* in_sizes, int n_in,
                              void* d_out, int out_size, void* d_ws, size_t ws_size,
                              hipStream_t stream) {
    const int*   x32    = (const int*)d_in[0];
    const int*   w32    = (const int*)d_in[1];
    const int*   bias   = (const int*)d_in[2];
    const float* wscale = (const float*)d_in[3];
    const float* iscale = (const float*)d_in[4];
    const float* oscale = (const float*)d_in[5];
    const int*   zp     = (const int*)d_in[6];
    int* out = (int*)d_out;

    const size_t need = (size_t)M_DIM * K_DIM + (size_t)N_DIM * K_DIM;  // 50.3 MB
    const size_t lds_bytes = 3 * (size_t)(ABUF + BBUF);                 // 98304

    if (ws_size >= need) {
        int8_t* x8 = (int8_t*)d_ws;
        int8_t* w8 = x8 + (size_t)M_DIM * K_DIM;
        pack_i8_kernel<<<2048, 256, 0, stream>>>(x32, x8, M_DIM * K_DIM);
        pack_i8_kernel<<<1024, 256, 0, stream>>>(w32, w8, N_DIM * K_DIM);
        (void)hipFuncSetAttribute((const void*)qgemm256_kernel,
                                  hipFuncAttributeMaxDynamicSharedMemorySize,
                                  (int)lds_bytes);
        qgemm256_kernel<<<NBLK, 512, lds_bytes, stream>>>(x8, w8, bias, wscale, iscale, oscale, zp, out);
    } else {
        qgemm_fallback<<<2048, 256, 0, stream>>>(x32, w32, bias, wscale, iscale, oscale, zp, out);
    }
}

// Round 5
// 187.553 us; speedup vs baseline: 1.1948x; 1.0736x over previous
//
#include <hip/hip_runtime.h>
#include <stdint.h>

// QuantizedLinear: out[N,OUT_F] = requant(int8gemm(x, W^T) + bias)
// x: [8192,4096] int8 (pushed int32), W: [4096,4096] int8 (pushed int32)
// out: int8 values stored as int32 (harness reads d_out as np.int32)
//
// r5: pack pre-pass writes FRAGMENT-ORDERED panels: for each (16-row x 64-k)
// subtile, 1024B with byte[l*16+j] = src[rb*16+(l&15)][kt*64+(l>>4)*16+j]
// (lane layout of mfma_i32_16x16x64_i8 operands, HW-verified r2/r4).
// GEMM: 256x256 tile, 8 waves (2Mx4N), per-wave 128x64, BK=64, 3-buffer ring,
// 2 phases x 16 MFMA, lane-linear conflict-free ds_reads, counted vmcnt,
// setprio, XCD-bijective swizzle.

#define M_DIM 8192
#define N_DIM 4096
#define K_DIM 4096
#define BM 256
#define BN 256
#define BKB 64                       // K elems (bytes) per tile
#define NKT (K_DIM / BKB)            // 64 k-tiles in panel layout
#define NT NKT
#define NBLK ((M_DIM / BM) * (N_DIM / BN))   // 32*16 = 512
#define ABUF (BM * BKB)              // 16 KiB
#define BBUF (BN * BKB)              // 16 KiB

using i32x4 = __attribute__((ext_vector_type(4))) int;

typedef const __attribute__((address_space(1))) uint32_t* gptr_t;
typedef __attribute__((address_space(3))) uint32_t* lptr_t;

__device__ __forceinline__ void gload_lds16(const void* g, void* l) {
    __builtin_amdgcn_global_load_lds((gptr_t)g, (lptr_t)l, 16, 0, 0);
}

__device__ __forceinline__ int pack4(i32x4 v) {
    return (int)(((unsigned)v.x & 0xFFu) | (((unsigned)v.y & 0xFFu) << 8) |
                 (((unsigned)v.z & 0xFFu) << 16) | (((unsigned)v.w) << 24));
}

// int32 [rows][K_DIM] -> fragment-ordered panels [rows/16][NKT][1024]
// block (rb,kt): byte[l*16+j] = (int8)src[rb*16 + (l&15)][kt*64 + (l>>4)*16 + j]
__global__ void pack_panels_kernel(const int* __restrict__ src, int8_t* __restrict__ dst,
                                   int n_blocks) {
    int gid = blockIdx.x * blockDim.x + threadIdx.x;
    int blk = gid >> 6;
    int l = gid & 63;
    if (blk >= n_blocks) return;
    int rb = blk >> 6;               // NKT = 64 k-tiles per row-block
    int kt = blk & (NKT - 1);
    const i32x4* s4 = (const i32x4*)(src + (size_t)(rb * 16 + (l & 15)) * K_DIM
                                         + kt * 64 + (l >> 4) * 16);
    i32x4 o;
    o.x = pack4(s4[0]); o.y = pack4(s4[1]); o.z = pack4(s4[2]); o.w = pack4(s4[3]);
    *(i32x4*)(dst + (size_t)blk * 1024 + l * 16) = o;
}

#define MFMA_I8(a, b, c) __builtin_amdgcn_mfma_i32_16x16x64_i8((a), (b), (c), 0, 0, 0)

// Lane-linear fragment reads: Acur/Bcur already include wave offset + lane*16.
// Compile-time 1024-multiples fold into ds_read offset immediates. Conflict-free.
#define FRAG_A(P, m) (*(const i32x4*)(Acur + ((P) * 4 + (m)) * 1024))
#define FRAG_B(n)    (*(const i32x4*)(Bcur + (n) * 1024))

// Phase P=0: read A m0-3 + all B (kept live), 16 MFMA into acc[0..3][*]
#define PHASE0(STAGE_STMTS, TAIL_STMTS)                                           \
  { i32x4 af0 = FRAG_A(0,0), af1 = FRAG_A(0,1), af2 = FRAG_A(0,2), af3 = FRAG_A(0,3); \
    bq0 = FRAG_B(0); bq1 = FRAG_B(1); bq2 = FRAG_B(2); bq3 = FRAG_B(3);           \
    STAGE_STMTS;                                                                  \
    __builtin_amdgcn_s_barrier();                                                 \
    asm volatile("s_waitcnt lgkmcnt(0)" ::: "memory");                            \
    __builtin_amdgcn_sched_barrier(0);                                            \
    __builtin_amdgcn_s_setprio(1);                                                \
    acc[0][0]=MFMA_I8(af0,bq0,acc[0][0]); acc[0][1]=MFMA_I8(af0,bq1,acc[0][1]);   \
    acc[0][2]=MFMA_I8(af0,bq2,acc[0][2]); acc[0][3]=MFMA_I8(af0,bq3,acc[0][3]);   \
    acc[1][0]=MFMA_I8(af1,bq0,acc[1][0]); acc[1][1]=MFMA_I8(af1,bq1,acc[1][1]);   \
    acc[1][2]=MFMA_I8(af1,bq2,acc[1][2]); acc[1][3]=MFMA_I8(af1,bq3,acc[1][3]);   \
    acc[2][0]=MFMA_I8(af2,bq0,acc[2][0]); acc[2][1]=MFMA_I8(af2,bq1,acc[2][1]);   \
    acc[2][2]=MFMA_I8(af2,bq2,acc[2][2]); acc[2][3]=MFMA_I8(af2,bq3,acc[2][3]);   \
    acc[3][0]=MFMA_I8(af3,bq0,acc[3][0]); acc[3][1]=MFMA_I8(af3,bq1,acc[3][1]);   \
    acc[3][2]=MFMA_I8(af3,bq2,acc[3][2]); acc[3][3]=MFMA_I8(af3,bq3,acc[3][3]);   \
    __builtin_amdgcn_s_setprio(0);                                                \
    TAIL_STMTS;                                                                   \
    __builtin_amdgcn_s_barrier(); }

// Phase P=1: read A m4-7, reuse B regs, 16 MFMA into acc[4..7][*]
#define PHASE1(STAGE_STMTS, TAIL_STMTS)                                           \
  { i32x4 af0 = FRAG_A(1,0), af1 = FRAG_A(1,1), af2 = FRAG_A(1,2), af3 = FRAG_A(1,3); \
    STAGE_STMTS;                                                                  \
    __builtin_amdgcn_s_barrier();                                                 \
    asm volatile("s_waitcnt lgkmcnt(0)" ::: "memory");                            \
    __builtin_amdgcn_sched_barrier(0);                                            \
    __builtin_amdgcn_s_setprio(1);                                                \
    acc[4][0]=MFMA_I8(af0,bq0,acc[4][0]); acc[4][1]=MFMA_I8(af0,bq1,acc[4][1]);   \
    acc[4][2]=MFMA_I8(af0,bq2,acc[4][2]); acc[4][3]=MFMA_I8(af0,bq3,acc[4][3]);   \
    acc[5][0]=MFMA_I8(af1,bq0,acc[5][0]); acc[5][1]=MFMA_I8(af1,bq1,acc[5][1]);   \
    acc[5][2]=MFMA_I8(af1,bq2,acc[5][2]); acc[5][3]=MFMA_I8(af1,bq3,acc[5][3]);   \
    acc[6][0]=MFMA_I8(af2,bq0,acc[6][0]); acc[6][1]=MFMA_I8(af2,bq1,acc[6][1]);   \
    acc[6][2]=MFMA_I8(af2,bq2,acc[6][2]); acc[6][3]=MFMA_I8(af2,bq3,acc[6][3]);   \
    acc[7][0]=MFMA_I8(af3,bq0,acc[7][0]); acc[7][1]=MFMA_I8(af3,bq1,acc[7][1]);   \
    acc[7][2]=MFMA_I8(af3,bq2,acc[7][2]); acc[7][3]=MFMA_I8(af3,bq3,acc[7][3]);   \
    __builtin_amdgcn_s_setprio(0);                                                \
    TAIL_STMTS;                                                                   \
    __builtin_amdgcn_s_barrier(); }

__global__ __launch_bounds__(512, 2)
void qgemm256_kernel(const int8_t* __restrict__ xp, const int8_t* __restrict__ wp,
                     const int* __restrict__ bias, const float* __restrict__ wscale,
                     const float* __restrict__ iscale, const float* __restrict__ oscale,
                     const int* __restrict__ zp, int* __restrict__ out) {
    extern __shared__ int8_t lds[];
    int8_t* As = lds;                 // 3 * 16 KiB
    int8_t* Bs = lds + 3 * ABUF;      // 3 * 16 KiB

    const int tid  = threadIdx.x;
    const int wave = tid >> 6;
    const int lane = tid & 63;

    // XCD-bijective swizzle (NBLK = 512, divisible by 8)
    int b = blockIdx.x;
    int s = (b & 7) * (NBLK >> 3) + (b >> 3);
    const int bcol = (s & 15) * BN;   // N_DIM/BN = 16
    const int brow = (s >> 4) * BM;

    const int wr = wave >> 2;         // 0..1  (M half, 128 rows)
    const int wc = wave & 3;          // 0..3  (N quarter, 64 cols)

    // ---- staging: wave stages A subtiles wave*2,wave*2+1 and B same.
    // Panel addr of subtile s, k-tile t: base + ((rb0+s)*NKT + t)*1024, lane*16.
    const int rb0 = brow >> 4;
    const int cb0 = bcol >> 4;
    const int8_t* AgP = xp + ((size_t)(rb0 + wave * 2) * NKT) * 1024 + lane * 16;
    const int8_t* BgP = wp + ((size_t)(cb0 + wave * 2) * NKT) * 1024 + lane * 16;
    const size_t substep = (size_t)NKT * 1024;   // next subtile, same k-tile
    const int aoff = wave * 2048;

    i32x4 acc[8][4] = {};
    i32x4 bq0, bq1, bq2, bq3;

    // ---- prologue: stage tile0 -> buf0, tile1 -> buf1 (4 loads/wave each) ----
    #pragma unroll
    for (int t0 = 0; t0 < 2; t0++) {
        int8_t* Ad = As + t0 * ABUF;
        int8_t* Bd = Bs + t0 * BBUF;
        gload_lds16(AgP + (size_t)t0 * 1024,           Ad + aoff);
        gload_lds16(AgP + substep + (size_t)t0 * 1024, Ad + aoff + 1024);
        gload_lds16(BgP + (size_t)t0 * 1024,           Bd + aoff);
        gload_lds16(BgP + substep + (size_t)t0 * 1024, Bd + aoff + 1024);
    }
    asm volatile("s_waitcnt vmcnt(4)" ::: "memory");   // tile0 landed; tile1 in flight
    __builtin_amdgcn_s_barrier();

    int cur = 0, stg = 2;
    // ---- main loop: t = 0 .. NT-3, staging tile t+2 into ring buffer ----
    for (int t = 0; t < NT - 2; ++t) {
        const int8_t* Acur = As + cur * ABUF + wr * 8192 + lane * 16;
        const int8_t* Bcur = Bs + cur * BBUF + wc * 4096 + lane * 16;
        int8_t* Astg = As + stg * ABUF;
        int8_t* Bstg = Bs + stg * BBUF;
        const size_t koff = (size_t)(t + 2) * 1024;

        PHASE0(
            { gload_lds16(AgP + koff,           Astg + aoff);
              gload_lds16(AgP + substep + koff, Astg + aoff + 1024); },
            ((void)0))
        PHASE1(
            { gload_lds16(BgP + koff,           Bstg + aoff);
              gload_lds16(BgP + substep + koff, Bstg + aoff + 1024); },
            asm volatile("s_waitcnt vmcnt(4)" ::: "memory"))   // tile t+1 landed

        cur = (cur == 2) ? 0 : cur + 1;
        stg = (stg == 2) ? 0 : stg + 1;
    }
    // ---- t = NT-2: no staging; drain so tile NT-1 is landed ----
    {
        const int8_t* Acur = As + cur * ABUF + wr * 8192 + lane * 16;
        const int8_t* Bcur = Bs + cur * BBUF + wc * 4096 + lane * 16;
        PHASE0(((void)0), ((void)0))
        PHASE1(((void)0), asm volatile("s_waitcnt vmcnt(0)" ::: "memory"))
        cur = (cur == 2) ? 0 : cur + 1;
    }
    // ---- t = NT-1: final compute ----
    {
        const int8_t* Acur = As + cur * ABUF + wr * 8192 + lane * 16;
        const int8_t* Bcur = Bs + cur * BBUF + wc * 4096 + lane * 16;
        PHASE0(((void)0), ((void)0))
        PHASE1(((void)0), ((void)0))
    }

    // ---- epilogue: out = clip(round((acc + bias) * (is*ws/os) + zp)) as int32 ----
    const float is_v = iscale[0];
    const float os_v = oscale[0];
    const float zpf = (float)zp[0];
    #pragma unroll
    for (int n = 0; n < 4; n++) {
        int col = bcol + wc * 64 + n * 16 + (lane & 15);
        float sf = (is_v * wscale[col]) / os_v;
        int bz = bias[col];
        #pragma unroll
        for (int m = 0; m < 8; m++) {
            int row0 = brow + wr * 128 + m * 16 + (lane >> 4) * 4;
            #pragma unroll
            for (int r = 0; r < 4; r++) {
                float v = (float)(acc[m][n][r] + bz) * sf + zpf;
                v = rintf(v);
                v = fminf(fmaxf(v, -128.0f), 127.0f);
                out[(size_t)(row0 + r) * N_DIM + col] = (int)v;
            }
        }
    }
}

// Fallback (no workspace): direct int32 consumption, 128^2 tile (round-2 proven).
__global__ void qgemm_fallback(const int* __restrict__ x32, const int* __restrict__ w32,
                               const int* __restrict__ bias, const float* __restrict__ wscale,
                               const float* __restrict__ iscale, const float* __restrict__ oscale,
                               const int* __restrict__ zp, int* __restrict__ out) {
    __shared__ int8_t As[128][64];
    __shared__ int8_t Bs[128][64];
    const int tid  = threadIdx.x;
    const int wave = tid >> 6;
    const int lane = tid & 63;
    int b = blockIdx.x;
    int s = (b & 7) * (gridDim.x >> 3) + (b >> 3);
    const int bcol = (s & 31) * 128;
    const int brow = (s >> 5) * 128;
    const int wr = wave >> 1;
    const int wc = wave & 1;
    i32x4 acc[4][4] = {};
    for (int kt = 0; kt < K_DIM; kt += 64) {
        int row = tid >> 1;
        int h = tid & 1;
        const i32x4* sa = (const i32x4*)(x32 + (size_t)(brow + row) * K_DIM + kt + h * 32);
        const i32x4* sb = (const i32x4*)(w32 + (size_t)(bcol + row) * K_DIM + kt + h * 32);
        int pa[8], pb[8];
        #pragma unroll
        for (int j = 0; j < 8; j++) { pa[j] = pack4(sa[j]); pb[j] = pack4(sb[j]); }
        *(i32x4*)&As[row][h * 32]      = *(i32x4*)&pa[0];
        *(i32x4*)&As[row][h * 32 + 16] = *(i32x4*)&pa[4];
        *(i32x4*)&Bs[row][h * 32]      = *(i32x4*)&pb[0];
        *(i32x4*)&Bs[row][h * 32 + 16] = *(i32x4*)&pb[4];
        __syncthreads();
        i32x4 a_frag[4], b_frag[4];
        #pragma unroll
        for (int m = 0; m < 4; m++)
            a_frag[m] = *(const i32x4*)&As[wr * 64 + m * 16 + (lane & 15)][(lane >> 4) * 16];
        #pragma unroll
        for (int n = 0; n < 4; n++)
            b_frag[n] = *(const i32x4*)&Bs[wc * 64 + n * 16 + (lane & 15)][(lane >> 4) * 16];
        #pragma unroll
        for (int m = 0; m < 4; m++)
            #pragma unroll
            for (int n = 0; n < 4; n++)
                acc[m][n] = MFMA_I8(a_frag[m], b_frag[n], acc[m][n]);
        __syncthreads();
    }
    const float is_v = iscale[0];
    const float os_v = oscale[0];
    const float zpf = (float)zp[0];
    #pragma unroll
    for (int n = 0; n < 4; n++) {
        int col = bcol + wc * 64 + n * 16 + (lane & 15);
        float sf = (is_v * wscale[col]) / os_v;
        int bz = bias[col];
        #pragma unroll
        for (int m = 0; m < 4; m++) {
            int row0 = brow + wr * 64 + m * 16 + (lane >> 4) * 4;
            #pragma unroll
            for (int r = 0; r < 4; r++) {
                float v = (float)(acc[m][n][r] + bz) * sf + zpf;
                v = rintf(v);
                v = fminf(fmaxf(v, -128.0f), 127.0f);
                out[(size_t)(row0 + r) * N_DIM + col] = (int)v;
            }
        }
    }
}

extern "C" void kernel_launch(void* const* d_in, const int* in_sizes, int n_in,
                              void* d_out, int out_size, void* d_ws, size_t ws_size,
                              hipStream_t stream) {
    const int*   x32    = (const int*)d_in[0];
    const int*   w32    = (const int*)d_in[1];
    const int*   bias   = (const int*)d_in[2];
    const float* wscale = (const float*)d_in[3];
    const float* iscale = (const float*)d_in[4];
    const float* oscale = (const float*)d_in[5];
    const int*   zp     = (const int*)d_in[6];
    int* out = (int*)d_out;

    const size_t need = (size_t)M_DIM * K_DIM + (size_t)N_DIM * K_DIM;  // 50.3 MB
    const size_t lds_bytes = 3 * (size_t)(ABUF + BBUF);                 // 98304

    if (ws_size >= need) {
        int8_t* xp = (int8_t*)d_ws;
        int8_t* wp = xp + (size_t)M_DIM * K_DIM;
        const int nblkA = (M_DIM / 16) * NKT;   // 32768
        const int nblkB = (N_DIM / 16) * NKT;   // 16384
        pack_panels_kernel<<<nblkA / 4, 256, 0, stream>>>(x32, xp, nblkA);
        pack_panels_kernel<<<nblkB / 4, 256, 0, stream>>>(w32, wp, nblkB);
        (void)hipFuncSetAttribute((const void*)qgemm256_kernel,
                                  hipFuncAttributeMaxDynamicSharedMemorySize,
                                  (int)lds_bytes);
        qgemm256_kernel<<<NBLK, 512, lds_bytes, stream>>>(xp, wp, bias, wscale, iscale, oscale, zp, out);
    } else {
        qgemm_fallback<<<2048, 256, 0, stream>>>(x32, w32, bias, wscale, iscale, oscale, zp, out);
    }
}

// Round 6
// 187.180 us; speedup vs baseline: 1.1971x; 1.0020x over previous
//
#include <hip/hip_runtime.h>
#include <stdint.h>

// QuantizedLinear: out[N,OUT_F] = requant(int8gemm(x, W^T) + bias)
// x: [8192,4096] int8 (pushed int32), W: [4096,4096] int8 (pushed int32)
// out: int8 values stored as int32 (harness reads d_out as np.int32)
//
// r6: mfma_i32_32x32x32_i8 (4404 TOPS ceiling vs 3944 for 16x16x64; half the
// instruction count). Pack pre-pass emits 32x32-subtile fragment-ordered
// panels: block[l*16+j] = src[rb*32+(l&31)][kt*32+(l>>5)*16+j].
// GEMM: 256x256 tile, 8 waves (2Mx4N), per-wave 128x64, BK=64 (2 k-subtiles),
// 3-buffer ring, 2 phases x 8 independent MFMA, lane-linear ds_reads,
// counted vmcnt, setprio, XCD-bijective swizzle.

#define M_DIM 8192
#define N_DIM 4096
#define K_DIM 4096
#define BM 256
#define BN 256
#define NKT2 (K_DIM / 32)            // 128 k-subtiles in panel layout
#define NT (K_DIM / 64)              // 64 K-tiles (2 subtiles each)
#define NBLK ((M_DIM / BM) * (N_DIM / BN))   // 32*16 = 512
#define ABUF (BM * 64)               // 16 KiB
#define BBUF (BN * 64)               // 16 KiB

using i32x4  = __attribute__((ext_vector_type(4))) int;
using i32x16 = __attribute__((ext_vector_type(16))) int;

typedef const __attribute__((address_space(1))) uint32_t* gptr_t;
typedef __attribute__((address_space(3))) uint32_t* lptr_t;

__device__ __forceinline__ void gload_lds16(const void* g, void* l) {
    __builtin_amdgcn_global_load_lds((gptr_t)g, (lptr_t)l, 16, 0, 0);
}

__device__ __forceinline__ int pack4(i32x4 v) {
    return (int)(((unsigned)v.x & 0xFFu) | (((unsigned)v.y & 0xFFu) << 8) |
                 (((unsigned)v.z & 0xFFu) << 16) | (((unsigned)v.w) << 24));
}

// int32 [rows][K_DIM] -> fragment-ordered panels [rows/32][NKT2][1024]
// block (rb,kt): byte[l*16+j] = (int8)src[rb*32 + (l&31)][kt*32 + (l>>5)*16 + j]
__global__ void pack_panels32_kernel(const int* __restrict__ src, int8_t* __restrict__ dst,
                                     int n_blocks) {
    int gid = blockIdx.x * blockDim.x + threadIdx.x;
    int blk = gid >> 6;
    int l = gid & 63;
    if (blk >= n_blocks) return;
    int rb = blk >> 7;               // / NKT2
    int kt = blk & (NKT2 - 1);
    const i32x4* s4 = (const i32x4*)(src + (size_t)(rb * 32 + (l & 31)) * K_DIM
                                         + kt * 32 + (l >> 5) * 16);
    i32x4 o;
    o.x = pack4(s4[0]); o.y = pack4(s4[1]); o.z = pack4(s4[2]); o.w = pack4(s4[3]);
    *(i32x4*)(dst + (size_t)blk * 1024 + l * 16) = o;
}

#define MFMA32(a, b, c) __builtin_amdgcn_mfma_i32_32x32x32_i8((a), (b), (c), 0, 0, 0)

// Lane-linear fragment reads; Acur/Bcur include wave offset + lane*16.
// r in 0..3 (32-row subtile), c in 0..1 (32-col subtile), k in 0..1 (32-k subtile).
#define FRAG_A(r, k) (*(const i32x4*)(Acur + (r) * 2048 + (k) * 1024))
#define FRAG_B(c, k) (*(const i32x4*)(Bcur + (c) * 2048 + (k) * 1024))

// Phase k: read 4 A + 2 B frags for k-subtile k; 8 independent MFMA.
#define PHASEK(k, STAGE_STMTS, TAIL_STMTS)                                        \
  { i32x4 a0 = FRAG_A(0,k), a1 = FRAG_A(1,k), a2 = FRAG_A(2,k), a3 = FRAG_A(3,k); \
    i32x4 b0 = FRAG_B(0,k), b1 = FRAG_B(1,k);                                     \
    STAGE_STMTS;                                                                  \
    __builtin_amdgcn_s_barrier();                                                 \
    asm volatile("s_waitcnt lgkmcnt(0)" ::: "memory");                            \
    __builtin_amdgcn_sched_barrier(0);                                            \
    __builtin_amdgcn_s_setprio(1);                                                \
    acc[0][0] = MFMA32(a0, b0, acc[0][0]); acc[0][1] = MFMA32(a0, b1, acc[0][1]); \
    acc[1][0] = MFMA32(a1, b0, acc[1][0]); acc[1][1] = MFMA32(a1, b1, acc[1][1]); \
    acc[2][0] = MFMA32(a2, b0, acc[2][0]); acc[2][1] = MFMA32(a2, b1, acc[2][1]); \
    acc[3][0] = MFMA32(a3, b0, acc[3][0]); acc[3][1] = MFMA32(a3, b1, acc[3][1]); \
    __builtin_amdgcn_s_setprio(0);                                                \
    TAIL_STMTS;                                                                   \
    __builtin_amdgcn_s_barrier(); }

__global__ __launch_bounds__(512, 2)
void qgemm32_kernel(const int8_t* __restrict__ xp, const int8_t* __restrict__ wp,
                    const int* __restrict__ bias, const float* __restrict__ wscale,
                    const float* __restrict__ iscale, const float* __restrict__ oscale,
                    const int* __restrict__ zp, int* __restrict__ out) {
    extern __shared__ int8_t lds[];
    int8_t* As = lds;                 // 3 * 16 KiB, layout [rsub 0..7][ksub 0..1][1024]
    int8_t* Bs = lds + 3 * ABUF;      // 3 * 16 KiB, layout [csub 0..7][ksub 0..1][1024]

    const int tid  = threadIdx.x;
    const int wave = tid >> 6;
    const int lane = tid & 63;

    // XCD-bijective swizzle (NBLK = 512, divisible by 8)
    int b = blockIdx.x;
    int s = (b & 7) * (NBLK >> 3) + (b >> 3);
    const int bcol = (s & 15) * BN;   // N_DIM/BN = 16
    const int brow = (s >> 4) * BM;

    const int wr = wave >> 2;         // 0..1  (M half, 128 rows = 4 rsubs)
    const int wc = wave & 3;          // 0..3  (N quarter, 64 cols = 2 csubs)

    // ---- staging: wave stages A rsub=wave (both ksubs), B csub=wave ----
    const int rb0 = brow >> 5;        // 8 rsubs per block tile
    const int cb0 = bcol >> 5;        // 8 csubs per block tile
    const int8_t* AgP = xp + ((size_t)(rb0 + wave) * NKT2) * 1024 + lane * 16;
    const int8_t* BgP = wp + ((size_t)(cb0 + wave) * NKT2) * 1024 + lane * 16;
    const int aoff = wave * 2048;

    i32x16 acc[4][2] = {};

    // ---- prologue: stage tile0 -> buf0, tile1 -> buf1 (4 loads/wave each) ----
    #pragma unroll
    for (int t0 = 0; t0 < 2; t0++) {
        int8_t* Ad = As + t0 * ABUF;
        int8_t* Bd = Bs + t0 * BBUF;
        gload_lds16(AgP + (size_t)(2 * t0) * 1024,     Ad + aoff);
        gload_lds16(AgP + (size_t)(2 * t0 + 1) * 1024, Ad + aoff + 1024);
        gload_lds16(BgP + (size_t)(2 * t0) * 1024,     Bd + aoff);
        gload_lds16(BgP + (size_t)(2 * t0 + 1) * 1024, Bd + aoff + 1024);
    }
    asm volatile("s_waitcnt vmcnt(4)" ::: "memory");   // tile0 landed; tile1 in flight
    __builtin_amdgcn_s_barrier();

    int cur = 0, stg = 2;
    // ---- main loop: t = 0 .. NT-3, staging tile t+2 into ring buffer ----
    for (int t = 0; t < NT - 2; ++t) {
        const int8_t* Acur = As + cur * ABUF + wr * 8192 + lane * 16;
        const int8_t* Bcur = Bs + cur * BBUF + wc * 4096 + lane * 16;
        int8_t* Astg = As + stg * ABUF;
        int8_t* Bstg = Bs + stg * BBUF;
        const size_t k0 = (size_t)(2 * (t + 2)) * 1024;

        PHASEK(0,
            { gload_lds16(AgP + k0,        Astg + aoff);
              gload_lds16(AgP + k0 + 1024, Astg + aoff + 1024); },
            ((void)0))
        PHASEK(1,
            { gload_lds16(BgP + k0,        Bstg + aoff);
              gload_lds16(BgP + k0 + 1024, Bstg + aoff + 1024); },
            asm volatile("s_waitcnt vmcnt(4)" ::: "memory"))   // tile t+1 landed

        cur = (cur == 2) ? 0 : cur + 1;
        stg = (stg == 2) ? 0 : stg + 1;
    }
    // ---- t = NT-2: no staging; drain so tile NT-1 is landed ----
    {
        const int8_t* Acur = As + cur * ABUF + wr * 8192 + lane * 16;
        const int8_t* Bcur = Bs + cur * BBUF + wc * 4096 + lane * 16;
        PHASEK(0, ((void)0), ((void)0))
        PHASEK(1, ((void)0), asm volatile("s_waitcnt vmcnt(0)" ::: "memory"))
        cur = (cur == 2) ? 0 : cur + 1;
    }
    // ---- t = NT-1: final compute ----
    {
        const int8_t* Acur = As + cur * ABUF + wr * 8192 + lane * 16;
        const int8_t* Bcur = Bs + cur * BBUF + wc * 4096 + lane * 16;
        PHASEK(0, ((void)0), ((void)0))
        PHASEK(1, ((void)0), ((void)0))
    }

    // ---- epilogue: out = clip(round((acc + bias) * (is*ws/os) + zp)) as int32 ----
    // 32x32 C/D layout (HW-verified): col = lane&31, row = (reg&3) + 8*(reg>>2) + 4*(lane>>5)
    const float is_v = iscale[0];
    const float os_v = oscale[0];
    const float zpf = (float)zp[0];
    #pragma unroll
    for (int c = 0; c < 2; c++) {
        int col = bcol + wc * 64 + c * 32 + (lane & 31);
        float sf = (is_v * wscale[col]) / os_v;
        int bz = bias[col];
        #pragma unroll
        for (int r = 0; r < 4; r++) {
            int rowb = brow + wr * 128 + r * 32 + 4 * (lane >> 5);
            #pragma unroll
            for (int reg = 0; reg < 16; reg++) {
                int row = rowb + (reg & 3) + 8 * (reg >> 2);
                float v = (float)(acc[r][c][reg] + bz) * sf + zpf;
                v = rintf(v);
                v = fminf(fmaxf(v, -128.0f), 127.0f);
                out[(size_t)row * N_DIM + col] = (int)v;
            }
        }
    }
}

#define MFMA_I8(a, b, c) __builtin_amdgcn_mfma_i32_16x16x64_i8((a), (b), (c), 0, 0, 0)

// Fallback (no workspace): direct int32 consumption, 128^2 tile (round-2 proven).
__global__ void qgemm_fallback(const int* __restrict__ x32, const int* __restrict__ w32,
                               const int* __restrict__ bias, const float* __restrict__ wscale,
                               const float* __restrict__ iscale, const float* __restrict__ oscale,
                               const int* __restrict__ zp, int* __restrict__ out) {
    __shared__ int8_t As[128][64];
    __shared__ int8_t Bs[128][64];
    const int tid  = threadIdx.x;
    const int wave = tid >> 6;
    const int lane = tid & 63;
    int b = blockIdx.x;
    int s = (b & 7) * (gridDim.x >> 3) + (b >> 3);
    const int bcol = (s & 31) * 128;
    const int brow = (s >> 5) * 128;
    const int wr = wave >> 1;
    const int wc = wave & 1;
    i32x4 acc[4][4] = {};
    for (int kt = 0; kt < K_DIM; kt += 64) {
        int row = tid >> 1;
        int h = tid & 1;
        const i32x4* sa = (const i32x4*)(x32 + (size_t)(brow + row) * K_DIM + kt + h * 32);
        const i32x4* sb = (const i32x4*)(w32 + (size_t)(bcol + row) * K_DIM + kt + h * 32);
        int pa[8], pb[8];
        #pragma unroll
        for (int j = 0; j < 8; j++) { pa[j] = pack4(sa[j]); pb[j] = pack4(sb[j]); }
        *(i32x4*)&As[row][h * 32]      = *(i32x4*)&pa[0];
        *(i32x4*)&As[row][h * 32 + 16] = *(i32x4*)&pa[4];
        *(i32x4*)&Bs[row][h * 32]      = *(i32x4*)&pb[0];
        *(i32x4*)&Bs[row][h * 32 + 16] = *(i32x4*)&pb[4];
        __syncthreads();
        i32x4 a_frag[4], b_frag[4];
        #pragma unroll
        for (int m = 0; m < 4; m++)
            a_frag[m] = *(const i32x4*)&As[wr * 64 + m * 16 + (lane & 15)][(lane >> 4) * 16];
        #pragma unroll
        for (int n = 0; n < 4; n++)
            b_frag[n] = *(const i32x4*)&Bs[wc * 64 + n * 16 + (lane & 15)][(lane >> 4) * 16];
        #pragma unroll
        for (int m = 0; m < 4; m++)
            #pragma unroll
            for (int n = 0; n < 4; n++)
                acc[m][n] = MFMA_I8(a_frag[m], b_frag[n], acc[m][n]);
        __syncthreads();
    }
    const float is_v = iscale[0];
    const float os_v = oscale[0];
    const float zpf = (float)zp[0];
    #pragma unroll
    for (int n = 0; n < 4; n++) {
        int col = bcol + wc * 64 + n * 16 + (lane & 15);
        float sf = (is_v * wscale[col]) / os_v;
        int bz = bias[col];
        #pragma unroll
        for (int m = 0; m < 4; m++) {
            int row0 = brow + wr * 64 + m * 16 + (lane >> 4) * 4;
            #pragma unroll
            for (int r = 0; r < 4; r++) {
                float v = (float)(acc[m][n][r] + bz) * sf + zpf;
                v = rintf(v);
                v = fminf(fmaxf(v, -128.0f), 127.0f);
                out[(size_t)(row0 + r) * N_DIM + col] = (int)v;
            }
        }
    }
}

extern "C" void kernel_launch(void* const* d_in, const int* in_sizes, int n_in,
                              void* d_out, int out_size, void* d_ws, size_t ws_size,
                              hipStream_t stream) {
    const int*   x32    = (const int*)d_in[0];
    const int*   w32    = (const int*)d_in[1];
    const int*   bias   = (const int*)d_in[2];
    const float* wscale = (const float*)d_in[3];
    const float* iscale = (const float*)d_in[4];
    const float* oscale = (const float*)d_in[5];
    const int*   zp     = (const int*)d_in[6];
    int* out = (int*)d_out;

    const size_t need = (size_t)M_DIM * K_DIM + (size_t)N_DIM * K_DIM;  // 50.3 MB
    const size_t lds_bytes = 3 * (size_t)(ABUF + BBUF);                 // 98304

    if (ws_size >= need) {
        int8_t* xp = (int8_t*)d_ws;
        int8_t* wp = xp + (size_t)M_DIM * K_DIM;
        const int nblkA = (M_DIM / 32) * NKT2;   // 32768
        const int nblkB = (N_DIM / 32) * NKT2;   // 16384
        pack_panels32_kernel<<<nblkA / 4, 256, 0, stream>>>(x32, xp, nblkA);
        pack_panels32_kernel<<<nblkB / 4, 256, 0, stream>>>(w32, wp, nblkB);
        (void)hipFuncSetAttribute((const void*)qgemm32_kernel,
                                  hipFuncAttributeMaxDynamicSharedMemorySize,
                                  (int)lds_bytes);
        qgemm32_kernel<<<NBLK, 512, lds_bytes, stream>>>(xp, wp, bias, wscale, iscale, oscale, zp, out);
    } else {
        qgemm_fallback<<<2048, 256, 0, stream>>>(x32, w32, bias, wscale, iscale, oscale, zp, out);
    }
}

// Round 7
// 186.374 us; speedup vs baseline: 1.2023x; 1.0043x over previous
//
#include <hip/hip_runtime.h>
#include <stdint.h>

// QuantizedLinear: out[N,OUT_F] = requant(int8gemm(x, W^T) + bias)
// x: [8192,4096] int8 (pushed int32), W: [4096,4096] int8 (pushed int32)
// out: int8 values stored as int32 (harness reads d_out as np.int32)
//
// r7: ONE barrier per K-tile (was 4). 3-buffer ring makes intra-tile barriers
// unnecessary (RAW/WAR/WAW all proven via vmcnt(4)+end-of-tile barrier and
// MFMA-operand-forced lgkm drain). Waves slide within the inter-barrier
// window so LDS-read bursts overlap MFMA bursts across waves.
// mfma_i32_32x32x32_i8, fragment-ordered panels, lane-linear ds_reads,
// counted vmcnt, setprio, XCD-bijective swizzle.

#define M_DIM 8192
#define N_DIM 4096
#define K_DIM 4096
#define BM 256
#define BN 256
#define NKT2 (K_DIM / 32)            // 128 k-subtiles in panel layout
#define NT (K_DIM / 64)              // 64 K-tiles (2 subtiles each)
#define NBLK ((M_DIM / BM) * (N_DIM / BN))   // 32*16 = 512
#define ABUF (BM * 64)               // 16 KiB
#define BBUF (BN * 64)               // 16 KiB

using i32x4  = __attribute__((ext_vector_type(4))) int;
using i32x16 = __attribute__((ext_vector_type(16))) int;

typedef const __attribute__((address_space(1))) uint32_t* gptr_t;
typedef __attribute__((address_space(3))) uint32_t* lptr_t;

__device__ __forceinline__ void gload_lds16(const void* g, void* l) {
    __builtin_amdgcn_global_load_lds((gptr_t)g, (lptr_t)l, 16, 0, 0);
}

__device__ __forceinline__ int pack4(i32x4 v) {
    return (int)(((unsigned)v.x & 0xFFu) | (((unsigned)v.y & 0xFFu) << 8) |
                 (((unsigned)v.z & 0xFFu) << 16) | (((unsigned)v.w) << 24));
}

// int32 [rows][K_DIM] -> fragment-ordered panels [rows/32][NKT2][1024]
// block (rb,kt): byte[l*16+j] = (int8)src[rb*32 + (l&31)][kt*32 + (l>>5)*16 + j]
__global__ void pack_panels32_kernel(const int* __restrict__ src, int8_t* __restrict__ dst,
                                     int n_blocks) {
    int gid = blockIdx.x * blockDim.x + threadIdx.x;
    int blk = gid >> 6;
    int l = gid & 63;
    if (blk >= n_blocks) return;
    int rb = blk >> 7;               // / NKT2
    int kt = blk & (NKT2 - 1);
    const i32x4* s4 = (const i32x4*)(src + (size_t)(rb * 32 + (l & 31)) * K_DIM
                                         + kt * 32 + (l >> 5) * 16);
    i32x4 o;
    o.x = pack4(s4[0]); o.y = pack4(s4[1]); o.z = pack4(s4[2]); o.w = pack4(s4[3]);
    *(i32x4*)(dst + (size_t)blk * 1024 + l * 16) = o;
}

#define MFMA32(a, b, c) __builtin_amdgcn_mfma_i32_32x32x32_i8((a), (b), (c), 0, 0, 0)

// Lane-linear fragment reads; Acur/Bcur include wave offset + lane*16.
#define FRAG_A(r, k) (*(const i32x4*)(Acur + (r) * 2048 + (k) * 1024))
#define FRAG_B(c, k) (*(const i32x4*)(Bcur + (c) * 2048 + (k) * 1024))

// One K-tile: 12 ds_reads + STAGE issues + 16 MFMA, then TAIL sync + 1 barrier.
// No intra-tile barriers; compiler handles ds_read->MFMA lgkmcnt.
#define KTILE(STAGE_A, STAGE_B, TAIL_STMTS)                                       \
  { i32x4 a0 = FRAG_A(0,0), a1 = FRAG_A(1,0), a2 = FRAG_A(2,0), a3 = FRAG_A(3,0); \
    i32x4 b0 = FRAG_B(0,0), b1 = FRAG_B(1,0);                                     \
    STAGE_A;                                                                      \
    i32x4 c0 = FRAG_A(0,1), c1 = FRAG_A(1,1), c2 = FRAG_A(2,1), c3 = FRAG_A(3,1); \
    i32x4 d0 = FRAG_B(0,1), d1 = FRAG_B(1,1);                                     \
    STAGE_B;                                                                      \
    __builtin_amdgcn_s_setprio(1);                                                \
    acc[0][0] = MFMA32(a0, b0, acc[0][0]); acc[0][1] = MFMA32(a0, b1, acc[0][1]); \
    acc[1][0] = MFMA32(a1, b0, acc[1][0]); acc[1][1] = MFMA32(a1, b1, acc[1][1]); \
    acc[2][0] = MFMA32(a2, b0, acc[2][0]); acc[2][1] = MFMA32(a2, b1, acc[2][1]); \
    acc[3][0] = MFMA32(a3, b0, acc[3][0]); acc[3][1] = MFMA32(a3, b1, acc[3][1]); \
    acc[0][0] = MFMA32(c0, d0, acc[0][0]); acc[0][1] = MFMA32(c0, d1, acc[0][1]); \
    acc[1][0] = MFMA32(c1, d0, acc[1][0]); acc[1][1] = MFMA32(c1, d1, acc[1][1]); \
    acc[2][0] = MFMA32(c2, d0, acc[2][0]); acc[2][1] = MFMA32(c2, d1, acc[2][1]); \
    acc[3][0] = MFMA32(c3, d0, acc[3][0]); acc[3][1] = MFMA32(c3, d1, acc[3][1]); \
    __builtin_amdgcn_s_setprio(0);                                                \
    TAIL_STMTS;                                                                   \
    __builtin_amdgcn_s_barrier(); }

__global__ __launch_bounds__(512, 2)
void qgemm32_kernel(const int8_t* __restrict__ xp, const int8_t* __restrict__ wp,
                    const int* __restrict__ bias, const float* __restrict__ wscale,
                    const float* __restrict__ iscale, const float* __restrict__ oscale,
                    const int* __restrict__ zp, int* __restrict__ out) {
    extern __shared__ int8_t lds[];
    int8_t* As = lds;                 // 3 * 16 KiB, layout [rsub 0..7][ksub 0..1][1024]
    int8_t* Bs = lds + 3 * ABUF;      // 3 * 16 KiB, layout [csub 0..7][ksub 0..1][1024]

    const int tid  = threadIdx.x;
    const int wave = tid >> 6;
    const int lane = tid & 63;

    // XCD-bijective swizzle (NBLK = 512, divisible by 8)
    int b = blockIdx.x;
    int s = (b & 7) * (NBLK >> 3) + (b >> 3);
    const int bcol = (s & 15) * BN;   // N_DIM/BN = 16
    const int brow = (s >> 4) * BM;

    const int wr = wave >> 2;         // 0..1  (M half, 128 rows = 4 rsubs)
    const int wc = wave & 3;          // 0..3  (N quarter, 64 cols = 2 csubs)

    // ---- staging: wave stages A rsub=wave (both ksubs), B csub=wave ----
    const int rb0 = brow >> 5;
    const int cb0 = bcol >> 5;
    const int8_t* AgP = xp + ((size_t)(rb0 + wave) * NKT2) * 1024 + lane * 16;
    const int8_t* BgP = wp + ((size_t)(cb0 + wave) * NKT2) * 1024 + lane * 16;
    const int aoff = wave * 2048;

    i32x16 acc[4][2] = {};

    // ---- prologue: stage tile0 -> buf0, tile1 -> buf1 (4 loads/wave each) ----
    #pragma unroll
    for (int t0 = 0; t0 < 2; t0++) {
        int8_t* Ad = As + t0 * ABUF;
        int8_t* Bd = Bs + t0 * BBUF;
        gload_lds16(AgP + (size_t)(2 * t0) * 1024,     Ad + aoff);
        gload_lds16(AgP + (size_t)(2 * t0 + 1) * 1024, Ad + aoff + 1024);
        gload_lds16(BgP + (size_t)(2 * t0) * 1024,     Bd + aoff);
        gload_lds16(BgP + (size_t)(2 * t0 + 1) * 1024, Bd + aoff + 1024);
    }
    asm volatile("s_waitcnt vmcnt(4)" ::: "memory");   // tile0 landed; tile1 in flight
    __builtin_amdgcn_s_barrier();

    int cur = 0, stg = 2;
    // ---- main loop: t = 0 .. NT-3, staging tile t+2 into ring buffer ----
    for (int t = 0; t < NT - 2; ++t) {
        const int8_t* Acur = As + cur * ABUF + wr * 8192 + lane * 16;
        const int8_t* Bcur = Bs + cur * BBUF + wc * 4096 + lane * 16;
        int8_t* Astg = As + stg * ABUF;
        int8_t* Bstg = Bs + stg * BBUF;
        const size_t k0 = (size_t)(2 * (t + 2)) * 1024;

        KTILE(
            { gload_lds16(AgP + k0,        Astg + aoff);
              gload_lds16(AgP + k0 + 1024, Astg + aoff + 1024); },
            { gload_lds16(BgP + k0,        Bstg + aoff);
              gload_lds16(BgP + k0 + 1024, Bstg + aoff + 1024); },
            asm volatile("s_waitcnt vmcnt(4)" ::: "memory"))   // tile t+1 landed

        cur = (cur == 2) ? 0 : cur + 1;
        stg = (stg == 2) ? 0 : stg + 1;
    }
    // ---- t = NT-2: no staging; drain so tile NT-1 is landed ----
    {
        const int8_t* Acur = As + cur * ABUF + wr * 8192 + lane * 16;
        const int8_t* Bcur = Bs + cur * BBUF + wc * 4096 + lane * 16;
        KTILE(((void)0), ((void)0),
              asm volatile("s_waitcnt vmcnt(0)" ::: "memory"))
        cur = (cur == 2) ? 0 : cur + 1;
    }
    // ---- t = NT-1: final compute (no tail sync needed) ----
    {
        const int8_t* Acur = As + cur * ABUF + wr * 8192 + lane * 16;
        const int8_t* Bcur = Bs + cur * BBUF + wc * 4096 + lane * 16;
        KTILE(((void)0), ((void)0), ((void)0))
    }

    // ---- epilogue: out = clip(round((acc + bias) * (is*ws/os) + zp)) as int32 ----
    // 32x32 C/D layout (HW-verified): col = lane&31, row = (reg&3) + 8*(reg>>2) + 4*(lane>>5)
    const float is_v = iscale[0];
    const float os_v = oscale[0];
    const float zpf = (float)zp[0];
    #pragma unroll
    for (int c = 0; c < 2; c++) {
        int col = bcol + wc * 64 + c * 32 + (lane & 31);
        float sf = (is_v * wscale[col]) / os_v;
        int bz = bias[col];
        #pragma unroll
        for (int r = 0; r < 4; r++) {
            int rowb = brow + wr * 128 + r * 32 + 4 * (lane >> 5);
            #pragma unroll
            for (int reg = 0; reg < 16; reg++) {
                int row = rowb + (reg & 3) + 8 * (reg >> 2);
                float v = (float)(acc[r][c][reg] + bz) * sf + zpf;
                v = rintf(v);
                v = fminf(fmaxf(v, -128.0f), 127.0f);
                out[(size_t)row * N_DIM + col] = (int)v;
            }
        }
    }
}

#define MFMA_I8(a, b, c) __builtin_amdgcn_mfma_i32_16x16x64_i8((a), (b), (c), 0, 0, 0)

// Fallback (no workspace): direct int32 consumption, 128^2 tile (round-2 proven).
__global__ void qgemm_fallback(const int* __restrict__ x32, const int* __restrict__ w32,
                               const int* __restrict__ bias, const float* __restrict__ wscale,
                               const float* __restrict__ iscale, const float* __restrict__ oscale,
                               const int* __restrict__ zp, int* __restrict__ out) {
    __shared__ int8_t As[128][64];
    __shared__ int8_t Bs[128][64];
    const int tid  = threadIdx.x;
    const int wave = tid >> 6;
    const int lane = tid & 63;
    int b = blockIdx.x;
    int s = (b & 7) * (gridDim.x >> 3) + (b >> 3);
    const int bcol = (s & 31) * 128;
    const int brow = (s >> 5) * 128;
    const int wr = wave >> 1;
    const int wc = wave & 1;
    i32x4 acc[4][4] = {};
    for (int kt = 0; kt < K_DIM; kt += 64) {
        int row = tid >> 1;
        int h = tid & 1;
        const i32x4* sa = (const i32x4*)(x32 + (size_t)(brow + row) * K_DIM + kt + h * 32);
        const i32x4* sb = (const i32x4*)(w32 + (size_t)(bcol + row) * K_DIM + kt + h * 32);
        int pa[8], pb[8];
        #pragma unroll
        for (int j = 0; j < 8; j++) { pa[j] = pack4(sa[j]); pb[j] = pack4(sb[j]); }
        *(i32x4*)&As[row][h * 32]      = *(i32x4*)&pa[0];
        *(i32x4*)&As[row][h * 32 + 16] = *(i32x4*)&pa[4];
        *(i32x4*)&Bs[row][h * 32]      = *(i32x4*)&pb[0];
        *(i32x4*)&Bs[row][h * 32 + 16] = *(i32x4*)&pb[4];
        __syncthreads();
        i32x4 a_frag[4], b_frag[4];
        #pragma unroll
        for (int m = 0; m < 4; m++)
            a_frag[m] = *(const i32x4*)&As[wr * 64 + m * 16 + (lane & 15)][(lane >> 4) * 16];
        #pragma unroll
        for (int n = 0; n < 4; n++)
            b_frag[n] = *(const i32x4*)&Bs[wc * 64 + n * 16 + (lane & 15)][(lane >> 4) * 16];
        #pragma unroll
        for (int m = 0; m < 4; m++)
            #pragma unroll
            for (int n = 0; n < 4; n++)
                acc[m][n] = MFMA_I8(a_frag[m], b_frag[n], acc[m][n]);
        __syncthreads();
    }
    const float is_v = iscale[0];
    const float os_v = oscale[0];
    const float zpf = (float)zp[0];
    #pragma unroll
    for (int n = 0; n < 4; n++) {
        int col = bcol + wc * 64 + n * 16 + (lane & 15);
        float sf = (is_v * wscale[col]) / os_v;
        int bz = bias[col];
        #pragma unroll
        for (int m = 0; m < 4; m++) {
            int row0 = brow + wr * 64 + m * 16 + (lane >> 4) * 4;
            #pragma unroll
            for (int r = 0; r < 4; r++) {
                float v = (float)(acc[m][n][r] + bz) * sf + zpf;
                v = rintf(v);
                v = fminf(fmaxf(v, -128.0f), 127.0f);
                out[(size_t)(row0 + r) * N_DIM + col] = (int)v;
            }
        }
    }
}

extern "C" void kernel_launch(void* const* d_in, const int* in_sizes, int n_in,
                              void* d_out, int out_size, void* d_ws, size_t ws_size,
                              hipStream_t stream) {
    const int*   x32    = (const int*)d_in[0];
    const int*   w32    = (const int*)d_in[1];
    const int*   bias   = (const int*)d_in[2];
    const float* wscale = (const float*)d_in[3];
    const float* iscale = (const float*)d_in[4];
    const float* oscale = (const float*)d_in[5];
    const int*   zp     = (const int*)d_in[6];
    int* out = (int*)d_out;

    const size_t need = (size_t)M_DIM * K_DIM + (size_t)N_DIM * K_DIM;  // 50.3 MB
    const size_t lds_bytes = 3 * (size_t)(ABUF + BBUF);                 // 98304

    if (ws_size >= need) {
        int8_t* xp = (int8_t*)d_ws;
        int8_t* wp = xp + (size_t)M_DIM * K_DIM;
        const int nblkA = (M_DIM / 32) * NKT2;   // 32768
        const int nblkB = (N_DIM / 32) * NKT2;   // 16384
        pack_panels32_kernel<<<nblkA / 4, 256, 0, stream>>>(x32, xp, nblkA);
        pack_panels32_kernel<<<nblkB / 4, 256, 0, stream>>>(w32, wp, nblkB);
        (void)hipFuncSetAttribute((const void*)qgemm32_kernel,
                                  hipFuncAttributeMaxDynamicSharedMemorySize,
                                  (int)lds_bytes);
        qgemm32_kernel<<<NBLK, 512, lds_bytes, stream>>>(xp, wp, bias, wscale, iscale, oscale, zp, out);
    } else {
        qgemm_fallback<<<2048, 256, 0, stream>>>(x32, w32, bias, wscale, iscale, oscale, zp, out);
    }
}

// Round 8
// 182.282 us; speedup vs baseline: 1.2293x; 1.0225x over previous
//
#include <hip/hip_runtime.h>
#include <stdint.h>

// QuantizedLinear: out[N,OUT_F] = requant(int8gemm(x, W^T) + bias)
// x: [8192,4096] int8 (pushed int32), W: [4096,4096] int8 (pushed int32)
// out: int8 values stored as int32 (harness reads d_out as np.int32)
//
// r8: register-prefetch pipeline. During tile t each wave ds_reads tile t+1's
// fragments (no consumer this tile -> no lgkm stall) and MFMAs tile t from
// registers. 4-slot LDS ring (128 KiB), ping-pong frag sets (static indices),
// one barrier/tile, counted vmcnt(4) (never 0 until tail), setprio,
// XCD-bijective swizzle. LDS pipe overlaps matrix pipe instead of serializing.

#define M_DIM 8192
#define N_DIM 4096
#define K_DIM 4096
#define BM 256
#define BN 256
#define NKT2 (K_DIM / 32)            // 128 k-subtiles in panel layout
#define NT (K_DIM / 64)              // 64 K-tiles (2 subtiles each)
#define NBLK ((M_DIM / BM) * (N_DIM / BN))   // 512
#define ABUF (BM * 64)               // 16 KiB per slot
#define BBUF (BN * 64)               // 16 KiB per slot

using i32x4  = __attribute__((ext_vector_type(4))) int;
using i32x16 = __attribute__((ext_vector_type(16))) int;

typedef const __attribute__((address_space(1))) uint32_t* gptr_t;
typedef __attribute__((address_space(3))) uint32_t* lptr_t;

__device__ __forceinline__ void gload_lds16(const void* g, void* l) {
    __builtin_amdgcn_global_load_lds((gptr_t)g, (lptr_t)l, 16, 0, 0);
}

__device__ __forceinline__ int pack4(i32x4 v) {
    return (int)(((unsigned)v.x & 0xFFu) | (((unsigned)v.y & 0xFFu) << 8) |
                 (((unsigned)v.z & 0xFFu) << 16) | (((unsigned)v.w) << 24));
}

// int32 [rows][K_DIM] -> fragment-ordered panels [rows/32][NKT2][1024]
// block (rb,kt): byte[l*16+j] = (int8)src[rb*32 + (l&31)][kt*32 + (l>>5)*16 + j]
__global__ void pack_panels32_kernel(const int* __restrict__ src, int8_t* __restrict__ dst,
                                     int n_blocks) {
    int gid = blockIdx.x * blockDim.x + threadIdx.x;
    int blk = gid >> 6;
    int l = gid & 63;
    if (blk >= n_blocks) return;
    int rb = blk >> 7;               // / NKT2
    int kt = blk & (NKT2 - 1);
    const i32x4* s4 = (const i32x4*)(src + (size_t)(rb * 32 + (l & 31)) * K_DIM
                                         + kt * 32 + (l >> 5) * 16);
    i32x4 o;
    o.x = pack4(s4[0]); o.y = pack4(s4[1]); o.z = pack4(s4[2]); o.w = pack4(s4[3]);
    *(i32x4*)(dst + (size_t)blk * 1024 + l * 16) = o;
}

#define MFMA32(a, b, c) __builtin_amdgcn_mfma_i32_32x32x32_i8((a), (b), (c), 0, 0, 0)

// Lane-linear fragment reads; bases include wave offset + lane*16.
// All slot/r/c/k offsets are compile-time immediates (max 56320 < 64K).
#define RA(S, R, K) (*(const i32x4*)(Ard + (S) * ABUF + (R) * 2048 + (K) * 1024))
#define RB(S, C, K) (*(const i32x4*)(Brd + (S) * BBUF + (C) * 2048 + (K) * 1024))

// Read one k-half of next tile's fragments into set NS (no consumer this tile).
#define READ_HALF(NS, SLOT, K)                                          \
    fA[NS][K][0] = RA(SLOT, 0, K); fA[NS][K][1] = RA(SLOT, 1, K);       \
    fA[NS][K][2] = RA(SLOT, 2, K); fA[NS][K][3] = RA(SLOT, 3, K);       \
    fB[NS][K][0] = RB(SLOT, 0, K); fB[NS][K][1] = RB(SLOT, 1, K);

// 8 independent MFMAs on set CS, k-half K.
#define MFMA_HALF(CS, K)                                                          \
    __builtin_amdgcn_s_setprio(1);                                                \
    acc[0][0] = MFMA32(fA[CS][K][0], fB[CS][K][0], acc[0][0]);                    \
    acc[0][1] = MFMA32(fA[CS][K][0], fB[CS][K][1], acc[0][1]);                    \
    acc[1][0] = MFMA32(fA[CS][K][1], fB[CS][K][0], acc[1][0]);                    \
    acc[1][1] = MFMA32(fA[CS][K][1], fB[CS][K][1], acc[1][1]);                    \
    acc[2][0] = MFMA32(fA[CS][K][2], fB[CS][K][0], acc[2][0]);                    \
    acc[2][1] = MFMA32(fA[CS][K][2], fB[CS][K][1], acc[2][1]);                    \
    acc[3][0] = MFMA32(fA[CS][K][3], fB[CS][K][0], acc[3][0]);                    \
    acc[3][1] = MFMA32(fA[CS][K][3], fB[CS][K][1], acc[3][1]);                    \
    __builtin_amdgcn_s_setprio(0);

// Stage tile into slot (4 gload_lds/wave), advance running global pointers.
#define STAGE(SLOT)                                                     \
    gload_lds16(AgS,        ldsA + (SLOT) * ABUF + waoff);              \
    gload_lds16(AgS + 1024, ldsA + (SLOT) * ABUF + waoff + 1024);       \
    gload_lds16(BgS,        ldsB + (SLOT) * BBUF + waoff);              \
    gload_lds16(BgS + 1024, ldsB + (SLOT) * BBUF + waoff + 1024);       \
    AgS += 2048; BgS += 2048;

// Steady-state tile: stage t+2, sync t+1 landed, prefetch t+1 frags, MFMA t.
#define TILE_STEADY(SLOT_STG, SLOT_NXT, CS, NS)                         \
  { STAGE(SLOT_STG)                                                     \
    asm volatile("s_waitcnt vmcnt(4)" ::: "memory");                    \
    __builtin_amdgcn_s_barrier();                                       \
    READ_HALF(NS, SLOT_NXT, 0)                                          \
    __builtin_amdgcn_sched_barrier(0);                                  \
    MFMA_HALF(CS, 0)                                                    \
    READ_HALF(NS, SLOT_NXT, 1)                                          \
    __builtin_amdgcn_sched_barrier(0);                                  \
    MFMA_HALF(CS, 1) }

__global__ __launch_bounds__(512, 2)
void qgemm32_kernel(const int8_t* __restrict__ xp, const int8_t* __restrict__ wp,
                    const int* __restrict__ bias, const float* __restrict__ wscale,
                    const float* __restrict__ iscale, const float* __restrict__ oscale,
                    const int* __restrict__ zp, int* __restrict__ out) {
    extern __shared__ int8_t lds[];
    int8_t* ldsA = lds;               // 4 slots * 16 KiB, [rsub 0..7][ksub 0..1][1024]
    int8_t* ldsB = lds + 4 * ABUF;    // 4 slots * 16 KiB, [csub 0..7][ksub 0..1][1024]

    const int tid  = threadIdx.x;
    const int wave = tid >> 6;
    const int lane = tid & 63;

    // XCD-bijective swizzle (NBLK = 512, divisible by 8)
    int b = blockIdx.x;
    int s = (b & 7) * (NBLK >> 3) + (b >> 3);
    const int bcol = (s & 15) * BN;   // N_DIM/BN = 16
    const int brow = (s >> 4) * BM;

    const int wr = wave >> 2;         // 0..1  (M half, 128 rows = 4 rsubs)
    const int wc = wave & 3;          // 0..3  (N quarter, 64 cols = 2 csubs)

    // staging sources (fragment-ordered panels; advance 2048 B per K-tile)
    const int rb0 = brow >> 5;
    const int cb0 = bcol >> 5;
    const int8_t* AgS = xp + ((size_t)(rb0 + wave) * NKT2) * 1024 + lane * 16;
    const int8_t* BgS = wp + ((size_t)(cb0 + wave) * NKT2) * 1024 + lane * 16;
    const int waoff = wave * 2048;

    // fragment read bases (all else folds into ds_read offset immediates)
    const int8_t* Ard = ldsA + wr * 8192 + lane * 16;
    const int8_t* Brd = ldsB + wc * 4096 + lane * 16;

    i32x16 acc[4][2] = {};
    i32x4 fA[2][2][4];                // [set][khalf][rsub] — all indices static
    i32x4 fB[2][2][2];                // [set][khalf][csub]

    // ---- prologue: stage tile0->slot0, tile1->slot1; land tile0; read set0 ----
    STAGE(0)
    STAGE(1)
    asm volatile("s_waitcnt vmcnt(4)" ::: "memory");   // tile0 landed
    __builtin_amdgcn_s_barrier();
    READ_HALF(0, 0, 0)
    READ_HALF(0, 0, 1)

    // ---- main loop: 15 iterations x 4 tiles (t = 0..59), staging t+2 ----
    for (int i = 0; i < 15; ++i) {
        TILE_STEADY(2, 1, 0, 1)       // t%4==0: stage slot2, next slot1
        TILE_STEADY(3, 2, 1, 0)       // t%4==1
        TILE_STEADY(0, 3, 0, 1)       // t%4==2
        TILE_STEADY(1, 0, 1, 0)       // t%4==3
    }
    // ---- t=60: stage 62->slot2 ---- / ---- t=61: stage 63->slot3 ----
    TILE_STEADY(2, 1, 0, 1)
    TILE_STEADY(3, 2, 1, 0)
    // ---- t=62: no stage; drain; prefetch tile63 (slot3); MFMA tile62 (set0) ----
    {
        asm volatile("s_waitcnt vmcnt(0)" ::: "memory");
        __builtin_amdgcn_s_barrier();
        READ_HALF(1, 3, 0)
        __builtin_amdgcn_sched_barrier(0);
        MFMA_HALF(0, 0)
        READ_HALF(1, 3, 1)
        __builtin_amdgcn_sched_barrier(0);
        MFMA_HALF(0, 1)
    }
    // ---- t=63: final MFMA (set1) ----
    MFMA_HALF(1, 0)
    MFMA_HALF(1, 1)

    // ---- epilogue: out = clip(round((acc + bias) * (is*ws/os) + zp)) as int32 ----
    // 32x32 C/D layout (HW-verified): col = lane&31, row = (reg&3) + 8*(reg>>2) + 4*(lane>>5)
    const float is_v = iscale[0];
    const float os_v = oscale[0];
    const float zpf = (float)zp[0];
    #pragma unroll
    for (int c = 0; c < 2; c++) {
        int col = bcol + wc * 64 + c * 32 + (lane & 31);
        float sf = (is_v * wscale[col]) / os_v;
        int bz = bias[col];
        #pragma unroll
        for (int r = 0; r < 4; r++) {
            int rowb = brow + wr * 128 + r * 32 + 4 * (lane >> 5);
            #pragma unroll
            for (int reg = 0; reg < 16; reg++) {
                int row = rowb + (reg & 3) + 8 * (reg >> 2);
                float v = (float)(acc[r][c][reg] + bz) * sf + zpf;
                v = rintf(v);
                v = fminf(fmaxf(v, -128.0f), 127.0f);
                out[(size_t)row * N_DIM + col] = (int)v;
            }
        }
    }
}

#define MFMA_I8(a, b, c) __builtin_amdgcn_mfma_i32_16x16x64_i8((a), (b), (c), 0, 0, 0)

// Fallback (no workspace): direct int32 consumption, 128^2 tile (round-2 proven).
__global__ void qgemm_fallback(const int* __restrict__ x32, const int* __restrict__ w32,
                               const int* __restrict__ bias, const float* __restrict__ wscale,
                               const float* __restrict__ iscale, const float* __restrict__ oscale,
                               const int* __restrict__ zp, int* __restrict__ out) {
    __shared__ int8_t As[128][64];
    __shared__ int8_t Bs[128][64];
    const int tid  = threadIdx.x;
    const int wave = tid >> 6;
    const int lane = tid & 63;
    int b = blockIdx.x;
    int s = (b & 7) * (gridDim.x >> 3) + (b >> 3);
    const int bcol = (s & 31) * 128;
    const int brow = (s >> 5) * 128;
    const int wr = wave >> 1;
    const int wc = wave & 1;
    i32x4 acc[4][4] = {};
    for (int kt = 0; kt < K_DIM; kt += 64) {
        int row = tid >> 1;
        int h = tid & 1;
        const i32x4* sa = (const i32x4*)(x32 + (size_t)(brow + row) * K_DIM + kt + h * 32);
        const i32x4* sb = (const i32x4*)(w32 + (size_t)(bcol + row) * K_DIM + kt + h * 32);
        int pa[8], pb[8];
        #pragma unroll
        for (int j = 0; j < 8; j++) { pa[j] = pack4(sa[j]); pb[j] = pack4(sb[j]); }
        *(i32x4*)&As[row][h * 32]      = *(i32x4*)&pa[0];
        *(i32x4*)&As[row][h * 32 + 16] = *(i32x4*)&pa[4];
        *(i32x4*)&Bs[row][h * 32]      = *(i32x4*)&pb[0];
        *(i32x4*)&Bs[row][h * 32 + 16] = *(i32x4*)&pb[4];
        __syncthreads();
        i32x4 a_frag[4], b_frag[4];
        #pragma unroll
        for (int m = 0; m < 4; m++)
            a_frag[m] = *(const i32x4*)&As[wr * 64 + m * 16 + (lane & 15)][(lane >> 4) * 16];
        #pragma unroll
        for (int n = 0; n < 4; n++)
            b_frag[n] = *(const i32x4*)&Bs[wc * 64 + n * 16 + (lane & 15)][(lane >> 4) * 16];
        #pragma unroll
        for (int m = 0; m < 4; m++)
            #pragma unroll
            for (int n = 0; n < 4; n++)
                acc[m][n] = MFMA_I8(a_frag[m], b_frag[n], acc[m][n]);
        __syncthreads();
    }
    const float is_v = iscale[0];
    const float os_v = oscale[0];
    const float zpf = (float)zp[0];
    #pragma unroll
    for (int n = 0; n < 4; n++) {
        int col = bcol + wc * 64 + n * 16 + (lane & 15);
        float sf = (is_v * wscale[col]) / os_v;
        int bz = bias[col];
        #pragma unroll
        for (int m = 0; m < 4; m++) {
            int row0 = brow + wr * 64 + m * 16 + (lane >> 4) * 4;
            #pragma unroll
            for (int r = 0; r < 4; r++) {
                float v = (float)(acc[m][n][r] + bz) * sf + zpf;
                v = rintf(v);
                v = fminf(fmaxf(v, -128.0f), 127.0f);
                out[(size_t)(row0 + r) * N_DIM + col] = (int)v;
            }
        }
    }
}

extern "C" void kernel_launch(void* const* d_in, const int* in_sizes, int n_in,
                              void* d_out, int out_size, void* d_ws, size_t ws_size,
                              hipStream_t stream) {
    const int*   x32    = (const int*)d_in[0];
    const int*   w32    = (const int*)d_in[1];
    const int*   bias   = (const int*)d_in[2];
    const float* wscale = (const float*)d_in[3];
    const float* iscale = (const float*)d_in[4];
    const float* oscale = (const float*)d_in[5];
    const int*   zp     = (const int*)d_in[6];
    int* out = (int*)d_out;

    const size_t need = (size_t)M_DIM * K_DIM + (size_t)N_DIM * K_DIM;  // 50.3 MB
    const size_t lds_bytes = 4 * (size_t)(ABUF + BBUF);                 // 131072

    if (ws_size >= need) {
        int8_t* xp = (int8_t*)d_ws;
        int8_t* wp = xp + (size_t)M_DIM * K_DIM;
        const int nblkA = (M_DIM / 32) * NKT2;   // 32768
        const int nblkB = (N_DIM / 32) * NKT2;   // 16384
        pack_panels32_kernel<<<nblkA / 4, 256, 0, stream>>>(x32, xp, nblkA);
        pack_panels32_kernel<<<nblkB / 4, 256, 0, stream>>>(w32, wp, nblkB);
        (void)hipFuncSetAttribute((const void*)qgemm32_kernel,
                                  hipFuncAttributeMaxDynamicSharedMemorySize,
                                  (int)lds_bytes);
        qgemm32_kernel<<<NBLK, 512, lds_bytes, stream>>>(xp, wp, bias, wscale, iscale, oscale, zp, out);
    } else {
        qgemm_fallback<<<2048, 256, 0, stream>>>(x32, w32, bias, wscale, iscale, oscale, zp, out);
    }
}